// Round 8
// baseline (1092.897 us; speedup 1.0000x reference)
//
#include <hip/hip_runtime.h>
#include <hip/hip_bf16.h>
#include <math.h>

#define PN 20000
#define DN 20000
#define SEQK 1024
#define EPPI 640000
#define EDDI 640000
#define EDTI 400000
#define NPAIRN 100000
#define RPB 128            // rows per bucket
#define NBUCK 157          // ceil(20000/128)
#define CH 4096            // edges per sort block
#define NBLKMAX 157        // ceil(640000/4096)
#define NPBLK 25           // ceil(100000/4096)

typedef float4 f4;
using bf16x8 = __attribute__((ext_vector_type(8))) __bf16;
using bf16x4 = __attribute__((ext_vector_type(4))) __bf16;
using bf16x2 = __attribute__((ext_vector_type(2))) __bf16;
using f32x4v = __attribute__((ext_vector_type(4))) float;

__device__ __forceinline__ f4 ld4(const float* p) { return *reinterpret_cast<const f4*>(p); }
__device__ __forceinline__ f4 ldb4(const __bf16* p) {
  bf16x4 v = *reinterpret_cast<const bf16x4*>(p);
  return make_float4((float)v[0], (float)v[1], (float)v[2], (float)v[3]);
}
__device__ __forceinline__ float2 ldb2(const __bf16* p) {
  bf16x2 v = *reinterpret_cast<const bf16x2*>(p);
  return make_float2((float)v[0], (float)v[1]);
}
__device__ __forceinline__ void stb4(__bf16* p, f4 v) {
  bf16x4 o;
  o[0] = (__bf16)v.x; o[1] = (__bf16)v.y; o[2] = (__bf16)v.z; o[3] = (__bf16)v.w;
  *reinterpret_cast<bf16x4*>(p) = o;
}
__device__ __forceinline__ void acc4(f4& a, f4 b) { a.x+=b.x; a.y+=b.y; a.z+=b.z; a.w+=b.w; }
__device__ __forceinline__ void acc4s(f4& a, f4 b, float s) { a.x+=s*b.x; a.y+=s*b.y; a.z+=s*b.z; a.w+=s*b.w; }

__device__ __forceinline__ void wave_ln(f4& x) {
  float s  = x.x + x.y + x.z + x.w;
  float ss = x.x*x.x + x.y*x.y + x.z*x.z + x.w*x.w;
#pragma unroll
  for (int o = 32; o; o >>= 1) { s += __shfl_xor(s, o, 64); ss += __shfl_xor(ss, o, 64); }
  float m = s * (1.f/256.f);
  float v = ss * (1.f/256.f) - m*m;
  float r = rsqrtf(v + 1e-5f);
  x.x = (x.x-m)*r; x.y = (x.y-m)*r; x.z = (x.z-m)*r; x.w = (x.w-m)*r;
}

// ---------------- fp32 -> bf16 converters ----------------
struct WPack { const float* src[16]; __bf16* dst[16]; int n[16]; };
__global__ __launch_bounds__(256) void convert_weights(WPack p) {
  const int wi = blockIdx.y;
  const int n = p.n[wi];
  const float* s = p.src[wi];
  __bf16* d = p.dst[wi];
  for (int i = (blockIdx.x * 256 + threadIdx.x) * 4; i < n; i += gridDim.x * 256 * 4) {
    f4 v = ld4(s + i);
    stb4(d + i, v);
  }
}

struct EPack { const float* src[3]; __bf16* dst[3]; int n[3]; };
__global__ __launch_bounds__(256) void convert_emb(EPack p) {
  const int wi = blockIdx.y;
  const int n = p.n[wi];
  const float* s = p.src[wi];
  __bf16* d = p.dst[wi];
  for (int i = (blockIdx.x * 256 + threadIdx.x) * 4; i < n; i += gridDim.x * 256 * 4) {
    f4 v = ld4(s + i);
    stb4(d + i, v);
  }
}

// ---------------- MFMA GEMM ----------------
__global__ __launch_bounds__(256) void gemm_mfma(
    const __bf16* __restrict__ X, const __bf16* __restrict__ Wt,
    const float* __restrict__ bias, __bf16* __restrict__ outb,
    int M, int K, int ostride, int act)
{
  const int tid = threadIdx.x;
  const int lane = tid & 63;
  const int w = tid >> 6;
  const int r0 = blockIdx.x * 64 + (w >> 1) * 32;
  const int c0 = blockIdx.y * 64 + (w & 1) * 32;
  const int l15 = lane & 15;
  const int lk = (lane >> 4) * 8;

  f32x4v acc[2][2];
#pragma unroll
  for (int m = 0; m < 2; ++m)
#pragma unroll
    for (int n = 0; n < 2; ++n) { acc[m][n][0]=0.f; acc[m][n][1]=0.f; acc[m][n][2]=0.f; acc[m][n][3]=0.f; }

  int ra = min(r0 + l15, M - 1);
  int rb = min(r0 + 16 + l15, M - 1);
  const __bf16* xa = X + (size_t)ra * K + lk;
  const __bf16* xb = X + (size_t)rb * K + lk;
  const __bf16* wa = Wt + (size_t)(c0 + l15) * K + lk;
  const __bf16* wc = Wt + (size_t)(c0 + 16 + l15) * K + lk;

  for (int k0 = 0; k0 < K; k0 += 32) {
    bf16x8 a0 = *reinterpret_cast<const bf16x8*>(xa + k0);
    bf16x8 a1 = *reinterpret_cast<const bf16x8*>(xb + k0);
    bf16x8 b0 = *reinterpret_cast<const bf16x8*>(wa + k0);
    bf16x8 b1 = *reinterpret_cast<const bf16x8*>(wc + k0);
    acc[0][0] = __builtin_amdgcn_mfma_f32_16x16x32_bf16(a0, b0, acc[0][0], 0, 0, 0);
    acc[0][1] = __builtin_amdgcn_mfma_f32_16x16x32_bf16(a0, b1, acc[0][1], 0, 0, 0);
    acc[1][0] = __builtin_amdgcn_mfma_f32_16x16x32_bf16(a1, b0, acc[1][0], 0, 0, 0);
    acc[1][1] = __builtin_amdgcn_mfma_f32_16x16x32_bf16(a1, b1, acc[1][1], 0, 0, 0);
  }

  const int rowbase = r0 + (lane >> 4) * 4;
#pragma unroll
  for (int m = 0; m < 2; ++m) {
#pragma unroll
    for (int i = 0; i < 4; ++i) {
      int row = rowbase + m * 16 + i;
      if (row >= M) continue;
#pragma unroll
      for (int n2 = 0; n2 < 2; ++n2) {
        int col = c0 + n2 * 16 + l15;
        float v = acc[m][n2][i];
        if (bias) v += bias[col];
        if (act == 1) v = fmaxf(v, 0.f);
        else if (act == 2) v = v > 0.f ? v : (expf(v) - 1.f);
        outb[(size_t)row * ostride + col] = (__bf16)v;
      }
    }
  }
}

// ---------------- contention-free two-level counting-sort CSR build ----------------
struct GPack {
  const int* src[4]; const int* dst[4]; int nE[4];
  int* col[4]; int* rowptr[4]; float* outdeg[4];  // dinvP,dinvD,icD,icP
  unsigned* stg[4];
  int* bh;      // [4][NBUCK][NBLKMAX]
  int* bbase;   // [4][NBUCK+1]
};

__global__ __launch_bounds__(256) void sort_hist(GPack g) {
  __shared__ int h[NBUCK];
  const int gi = blockIdx.y, blk = blockIdx.x;
  const int t = threadIdx.x;
  for (int i = t; i < NBUCK; i += 256) h[i] = 0;
  __syncthreads();
  const int base = blk * CH, nE = g.nE[gi];
  const int* dst = g.dst[gi];
#pragma unroll
  for (int i = 0; i < CH / 256; ++i) {
    int e = base + i * 256 + t;
    if (e < nE) atomicAdd(&h[dst[e] >> 7], 1);
  }
  __syncthreads();
  int* bh = g.bh + (size_t)gi * NBUCK * NBLKMAX;
  for (int i = t; i < NBUCK; i += 256) bh[i * NBLKMAX + blk] = h[i];
}

__global__ __launch_bounds__(1024) void sort_scan(GPack g) {
  __shared__ int sums[1024];
  const int gi = blockIdx.y;
  int* bh = g.bh + (size_t)gi * NBUCK * NBLKMAX;
  int* bbase = g.bbase + gi * (NBUCK + 1);
  const int L = NBUCK * NBLKMAX;
  const int t = threadIdx.x;
  const int chunk = (L + 1023) / 1024;
  const int b = t * chunk;
  const int e = min(b + chunk, L);
  int s = 0;
  for (int i = b; i < e; ++i) s += bh[i];
  sums[t] = s;
  __syncthreads();
  for (int o = 1; o < 1024; o <<= 1) {
    int u = (t >= o) ? sums[t - o] : 0;
    __syncthreads();
    sums[t] += u;
    __syncthreads();
  }
  int run = sums[t] - s;
  for (int i = b; i < e; ++i) {
    if (i % NBLKMAX == 0) bbase[i / NBLKMAX] = run;
    int old = bh[i];
    bh[i] = run;
    run += old;
  }
  if (t == 0) bbase[NBUCK] = g.nE[gi];
}

__global__ __launch_bounds__(256) void sort_scatter(GPack g) {
  __shared__ int cur[NBUCK];
  const int gi = blockIdx.y, blk = blockIdx.x;
  const int t = threadIdx.x;
  const int* bh = g.bh + (size_t)gi * NBUCK * NBLKMAX;
  for (int i = t; i < NBUCK; i += 256) cur[i] = bh[i * NBLKMAX + blk];
  __syncthreads();
  const int base = blk * CH, nE = g.nE[gi];
  const int* src = g.src[gi];
  const int* dst = g.dst[gi];
  unsigned* stg = g.stg[gi];
#pragma unroll
  for (int i = 0; i < CH / 256; ++i) {
    int e = base + i * 256 + t;
    if (e < nE) {
      int d = dst[e];
      int bkt = d >> 7;
      int pos = atomicAdd(&cur[bkt], 1);
      stg[pos] = ((unsigned)src[e] << 7) | (unsigned)(d & 127);
    }
  }
}

__global__ __launch_bounds__(256) void bucket_csr(GPack g) {
  const int gi = blockIdx.y;
  const int b = blockIdx.x;
  const int base = g.bbase[gi * (NBUCK + 1) + b];
  const int cnt  = g.bbase[gi * (NBUCK + 1) + b + 1] - base;
  __shared__ int h[RPB], sc[RPB];
  const int t = threadIdx.x;
  if (t < RPB) h[t] = 0;
  __syncthreads();
  const unsigned* st = g.stg[gi] + base;
  const int row0 = b * RPB;
  for (int i = t; i < cnt; i += 256) atomicAdd(&h[st[i] & 127u], 1);
  __syncthreads();
  if (t == 0) { int run = 0; for (int r = 0; r < RPB; ++r) { sc[r] = run; run += h[r]; } }
  __syncthreads();
  const int rows = min(RPB, PN - row0);
  if (t < rows) {
    g.rowptr[gi][row0 + t] = base + sc[t];
    float c = (float)h[t];
    g.outdeg[gi][row0 + t] = (gi < 2) ? rsqrtf(c + 1.f) : (1.f / fmaxf(c, 1.f));
  }
  if (b == 0 && t == 0) g.rowptr[gi][PN] = g.nE[gi];
  __syncthreads();
  if (t < RPB) h[t] = sc[t];
  __syncthreads();
  for (int i = t; i < cnt; i += 256) {
    unsigned v = st[i];
    int pos = atomicAdd(&h[v & 127u], 1);
    g.col[gi][base + pos] = (int)(v >> 7);
  }
}

// ---------------- pair sort by idx1 bucket ----------------
__global__ __launch_bounds__(256) void psort_hist(const int* __restrict__ idx1, int* __restrict__ ph) {
  __shared__ int h[NBUCK];
  const int blk = blockIdx.x, t = threadIdx.x;
  for (int i = t; i < NBUCK; i += 256) h[i] = 0;
  __syncthreads();
  const int base = blk * CH;
#pragma unroll
  for (int i = 0; i < CH / 256; ++i) {
    int e = base + i * 256 + t;
    if (e < NPAIRN) atomicAdd(&h[idx1[e] >> 7], 1);
  }
  __syncthreads();
  for (int i = t; i < NBUCK; i += 256) ph[i * NPBLK + blk] = h[i];
}

__global__ __launch_bounds__(1024) void psort_scan(int* __restrict__ ph) {
  __shared__ int sums[1024];
  const int L = NBUCK * NPBLK;
  const int t = threadIdx.x;
  const int chunk = (L + 1023) / 1024;
  const int b = t * chunk;
  const int e = min(b + chunk, L);
  int s = 0;
  for (int i = b; i < e; ++i) s += ph[i];
  sums[t] = s;
  __syncthreads();
  for (int o = 1; o < 1024; o <<= 1) {
    int u = (t >= o) ? sums[t - o] : 0;
    __syncthreads();
    sums[t] += u;
    __syncthreads();
  }
  int run = sums[t] - s;
  for (int i = b; i < e; ++i) { int old = ph[i]; ph[i] = run; run += old; }
}

__global__ __launch_bounds__(256) void psort_scatter(
    const int* __restrict__ idx1, const int* __restrict__ idx2,
    const int* __restrict__ ph, uint2* __restrict__ stg) {
  __shared__ int cur[NBUCK];
  const int blk = blockIdx.x, t = threadIdx.x;
  for (int i = t; i < NBUCK; i += 256) cur[i] = ph[i * NPBLK + blk];
  __syncthreads();
  const int base = blk * CH;
#pragma unroll
  for (int i = 0; i < CH / 256; ++i) {
    int e = base + i * 256 + t;
    if (e < NPAIRN) {
      int d = idx1[e];
      int pos = atomicAdd(&cur[d >> 7], 1);
      stg[pos] = make_uint2(((unsigned)d << 17) | (unsigned)e, (unsigned)idx2[e]);
    }
  }
}

// ---------------- gather half (128 feats) -> fp32 Acc; dinv=null => plain sum ----------------
__global__ __launch_bounds__(256) void gather_half(
    const int* __restrict__ rp, const int* __restrict__ cl,
    const float* __restrict__ dinv,
    const __bf16* __restrict__ T, int tstride, int foff,
    float* __restrict__ Acc, int n)
{
  int row = (blockIdx.x * blockDim.x + threadIdx.x) >> 6;
  if (row >= n) return;
  int lane = threadIdx.x & 63;
  int o = foff + lane * 2;
  int beg = rp[row], end = rp[row + 1];
  float a0 = 0.f, a1 = 0.f;
  int j = beg;
  if (dinv) {
    float dd = dinv[row];
    for (; j + 3 < end; j += 4) {
      int s0 = cl[j], s1 = cl[j+1], s2 = cl[j+2], s3 = cl[j+3];
      float n0 = dd*dinv[s0], n1 = dd*dinv[s1], n2 = dd*dinv[s2], n3 = dd*dinv[s3];
      float2 t0 = ldb2(T + (size_t)s0 * tstride + o);
      float2 t1 = ldb2(T + (size_t)s1 * tstride + o);
      float2 t2 = ldb2(T + (size_t)s2 * tstride + o);
      float2 t3 = ldb2(T + (size_t)s3 * tstride + o);
      a0 += n0*t0.x + n1*t1.x + n2*t2.x + n3*t3.x;
      a1 += n0*t0.y + n1*t1.y + n2*t2.y + n3*t3.y;
    }
    for (; j < end; ++j) {
      int s = cl[j];
      float nn = dd * dinv[s];
      float2 t = ldb2(T + (size_t)s * tstride + o);
      a0 += nn*t.x; a1 += nn*t.y;
    }
  } else {
    for (; j + 3 < end; j += 4) {
      int s0 = cl[j], s1 = cl[j+1], s2 = cl[j+2], s3 = cl[j+3];
      float2 t0 = ldb2(T + (size_t)s0 * tstride + o);
      float2 t1 = ldb2(T + (size_t)s1 * tstride + o);
      float2 t2 = ldb2(T + (size_t)s2 * tstride + o);
      float2 t3 = ldb2(T + (size_t)s3 * tstride + o);
      a0 += t0.x + t1.x + t2.x + t3.x;
      a1 += t0.y + t1.y + t2.y + t3.y;
    }
    for (; j < end; ++j) {
      float2 t = ldb2(T + (size_t)cl[j] * tstride + o);
      a0 += t.x; a1 += t.y;
    }
  }
  *reinterpret_cast<float2*>(Acc + (size_t)row * 256 + o) = make_float2(a0, a1);
}

// ---------------- combine: out = act( LN( AccG + dinv^2*T + gb + linb + L + ic*AccS )[*lw+lb] ) ----
__global__ __launch_bounds__(256) void combine_ln2(
    const float* __restrict__ AccG, const __bf16* __restrict__ T, int tstride,
    const float* __restrict__ dinv, const float* __restrict__ gb, const float* __restrict__ linb,
    const __bf16* __restrict__ L,
    const float* __restrict__ AccS, const float* __restrict__ ic,
    const float* __restrict__ lw, const float* __restrict__ lb,
    __bf16* __restrict__ out, int ostride, int n, int act)
{
  int row = (blockIdx.x * blockDim.x + threadIdx.x) >> 6;
  if (row >= n) return;
  int lane = threadIdx.x & 63;
  int o = lane * 4;
  f4 x = ld4(AccG + (size_t)row * 256 + o);
  float dd = dinv[row];
  acc4s(x, ldb4(T + (size_t)row * tstride + o), dd * dd);
  acc4(x, ld4(gb + o));
  if (linb) acc4(x, ld4(linb + o));
  acc4(x, ldb4(L + (size_t)row * tstride + o));
  if (AccS) acc4s(x, ld4(AccS + (size_t)row * 256 + o), ic[row]);
  wave_ln(x);
  if (lw) {
    f4 w = ld4(lw + o), b = ld4(lb + o);
    x.x = x.x*w.x + b.x; x.y = x.y*w.y + b.y; x.z = x.z*w.z + b.z; x.w = x.w*w.w + b.w;
  }
  if (act == 1) {
    x.x = fmaxf(x.x, 0.f); x.y = fmaxf(x.y, 0.f); x.z = fmaxf(x.z, 0.f); x.w = fmaxf(x.w, 0.f);
  }
  stb4(out + (size_t)row * ostride + o, x);
}

// ---------------- fp = elu(LN(x_seq)) ----------------
__global__ __launch_bounds__(256) void ln_elu(const __bf16* __restrict__ in, __bf16* __restrict__ out, int n) {
  int row = (blockIdx.x * blockDim.x + threadIdx.x) >> 6;
  if (row >= n) return;
  int lane = threadIdx.x & 63;
  int o = lane * 4;
  f4 x = ldb4(in + (size_t)row * 256 + o);
  wave_ln(x);
  x.x = x.x > 0.f ? x.x : expf(x.x)-1.f;
  x.y = x.y > 0.f ? x.y : expf(x.y)-1.f;
  x.z = x.z > 0.f ? x.z : expf(x.z)-1.f;
  x.w = x.w > 0.f ? x.w : expf(x.w)-1.f;
  stb4(out + (size_t)row * 256 + o, x);
}

// ---------------- pair epilogue over idx1-sorted pairs ----------------
__global__ __launch_bounds__(256) void pair_kernel(
    const __bf16* __restrict__ PK, const uint2* __restrict__ sp,
    const float* __restrict__ wR, const float* __restrict__ wI,
    float* __restrict__ out, int npair)
{
  int widx = (blockIdx.x * blockDim.x + threadIdx.x) >> 6;
  if (widx >= npair) return;
  int lane = threadIdx.x & 63;
  int f = lane * 4;
  uint2 e = sp[widx];
  int i1  = (int)(e.x >> 17);
  int wid = (int)(e.x & 131071u);
  int i2  = (int)e.y;
  const __bf16* r1 = PK + (size_t)i1 * 1024;
  const __bf16* r2 = PK + (size_t)i2 * 1024;

  f4 R1 = ldb4(r1 + f);        acc4(R1, ldb4(r2 + 256 + f)); wave_ln(R1);
  f4 I1 = ldb4(r1 + 512 + f);  acc4(I1, ldb4(r2 + 768 + f)); wave_ln(I1);
  f4 R2 = ldb4(r1 + 768 + f);  acc4(R2, ldb4(r2 + 512 + f)); wave_ln(R2);
  f4 I2 = ldb4(r1 + 256 + f);  acc4(I2, ldb4(r2 + f));       wave_ln(I2);

  f4 R, I;
  R.x = R1.x*R2.x - I1.x*I2.x;  I.x = R1.x*I2.x + I1.x*R2.x;
  R.y = R1.y*R2.y - I1.y*I2.y;  I.y = R1.y*I2.y + I1.y*R2.y;
  R.z = R1.z*R2.z - I1.z*I2.z;  I.z = R1.z*I2.z + I1.z*R2.z;
  R.w = R1.w*R2.w - I1.w*I2.w;  I.w = R1.w*I2.w + I1.w*R2.w;
  wave_ln(R); wave_ln(I);

  f4 wr = ld4(wR + f), wi = ld4(wI + f);
  float r_ = R.x*wr.x + I.x*wi.x + R.y*wr.y + I.y*wi.y
           + R.z*wr.z + I.z*wi.z + R.w*wr.w + I.w*wi.w;
  float i_ = I.x*wr.x - R.x*wi.x + I.y*wr.y - R.y*wi.y
           + I.z*wr.z - R.z*wi.z + I.w*wr.w - R.w*wi.w;
  float t = r_ + i_;
#pragma unroll
  for (int o = 32; o; o >>= 1) t += __shfl_xor(t, o, 64);
  if (lane == 0) out[wid] = 1.f / (1.f + expf(-t));
}

extern "C" void kernel_launch(void* const* d_in, const int* in_sizes, int n_in,
                              void* d_out, int out_size, void* d_ws, size_t ws_size,
                              hipStream_t stream) {
  (void)in_sizes; (void)n_in; (void)out_size; (void)ws_size;
  const float* seq        = (const float*)d_in[0];
  const int*   ppi        = (const int*)d_in[1];
  const int*   ddi        = (const int*)d_in[2];
  const int*   dti        = (const int*)d_in[3];
  const int*   idx1       = (const int*)d_in[4];
  const int*   idx2       = (const int*)d_in[5];
  const float* seq_init_W = (const float*)d_in[6];
  const float* gs1_gcn_W  = (const float*)d_in[7];
  const float* gs1_gcn_b  = (const float*)d_in[8];
  const float* gs1_lin_W  = (const float*)d_in[9];
  const float* gs1_ln_w   = (const float*)d_in[10];
  const float* gs1_ln_b   = (const float*)d_in[11];
  const float* gs2_gcn_W  = (const float*)d_in[12];
  const float* gs2_gcn_b  = (const float*)d_in[13];
  const float* gs2_lin_W  = (const float*)d_in[14];
  const float* gs2_ln_w   = (const float*)d_in[15];
  const float* gs2_ln_b   = (const float*)d_in[16];
  const float* drug_emb   = (const float*)d_in[17];
  const float* prot_emb   = (const float*)d_in[18];
  const float* pp1_W = (const float*)d_in[19]; const float* pp1_b = (const float*)d_in[20];
  const float* td1_W = (const float*)d_in[21]; const float* td1_b = (const float*)d_in[22];
  const float* pr1_W = (const float*)d_in[23]; const float* pr1_b = (const float*)d_in[24];
  const float* dd1_W = (const float*)d_in[25]; const float* dd1_b = (const float*)d_in[26];
  const float* dt1_W = (const float*)d_in[27]; const float* dt1_b = (const float*)d_in[28];
  const float* dr1_W = (const float*)d_in[29]; const float* dr1_b = (const float*)d_in[30];
  const float* pp2_W = (const float*)d_in[31]; const float* pp2_b = (const float*)d_in[32];
  const float* td2_W = (const float*)d_in[33]; const float* td2_b = (const float*)d_in[34];
  const float* pr2_W = (const float*)d_in[35]; const float* pr2_b = (const float*)d_in[36];
  const float* seq_fc_W  = (const float*)d_in[43];
  const float* skip_fc_W = (const float*)d_in[44];
  const float* wR = (const float*)d_in[45];
  const float* wI = (const float*)d_in[46];
  float* outp = (float*)d_out;

  // ---------------- workspace layout ----------------
  char* base = (char*)d_ws;
  unsigned* stgP  = (unsigned*)base;                 // EPPI
  unsigned* stgD  = stgP + EPPI;
  unsigned* stgTD = stgD + EDDI;
  unsigned* stgTP = stgTD + EDTI;
  int* colP  = (int*)(stgTP + EDTI);
  int* colD  = colP + EPPI;
  int* colTD = colD + EDDI;
  int* colTP = colTD + EDTI;
  int* rowptrP  = colTP + EDTI;
  int* rowptrD  = rowptrP + PN + 1;
  int* rowptrTD = rowptrD + PN + 1;
  int* rowptrTP = rowptrTD + PN + 1;
  float* dinvP = (float*)(rowptrTP + PN + 1);
  float* dinvD = dinvP + PN;
  float* icD   = dinvD + PN;
  float* icP   = icD + PN;
  int* bh    = (int*)(icP + PN);                     // 4*NBUCK*NBLKMAX
  int* bbase = bh + 4 * NBUCK * NBLKMAX;             // 4*(NBUCK+1)
  int* ph    = bbase + 4 * (NBUCK + 1);              // NBUCK*NPBLK

  unsigned long long waddr = (unsigned long long)(ph + NBUCK * NPBLK);
  waddr = (waddr + 63ULL) & ~63ULL;
  __bf16* wb = (__bf16*)waddr;
  __bf16* Wseq  = wb;                           // [256,1024]
  __bf16* pair0 = Wseq + 256*1024;              // each pair [512,256]
  __bf16* pair1 = pair0 + 512*256;
  __bf16* pair2 = pair1 + 512*256;
  __bf16* pair3 = pair2 + 512*256;
  __bf16* pair4 = pair3 + 512*256;
  __bf16* sing  = pair4 + 512*256;
  __bf16* Wdt1  = sing;
  __bf16* Wtd1  = sing + 65536;
  __bf16* Wtd2  = sing + 2*65536;
  __bf16* Wsfc  = sing + 3*65536;
  __bf16* Wskp  = sing + 4*65536;
  const size_t NB = (size_t)PN * 256;
  __bf16* Ed    = sing + 5*65536;               // [20000,256]
  __bf16* Ep    = Ed + NB;
  __bf16* TL    = Ep + NB;                      // [20000,512]
  __bf16* B0    = TL + (size_t)PN*512;          // x_seq
  __bf16* B2    = B0 + NB;                      // h -> d
  __bf16* B4    = B2 + NB;                      // proj -> fp
  __bf16* B5    = B4 + NB;                      // p
  __bf16* PK    = B5 + NB;                      // [20000][1024]; aliased as Eseq before P3
  __bf16* Eseq  = PK;                           // [20000,1024] (dead after P1)
  float*  AccG  = (float*)(PK + (size_t)PN * 1024);  // [20000,256] fp32
  float*  AccS  = AccG + NB;                         // [20000,256] fp32
  uint2*  pstg  = (uint2*)(AccS + NB);               // NPAIRN sorted pairs

  const dim3 blk(256);
  const dim3 g256(313, 4);
  const dim3 g512(313, 8);
  const dim3 rgrid((PN + 3) / 4);
  const dim3 sgrid(NBLKMAX, 4);
  const dim3 bgrid(NBUCK, 4);

  auto GEMM = [&](const __bf16* X, const __bf16* Wt, const float* bias,
                  __bf16* outb, int K, int ostride, int act, dim3 grid) {
    hipLaunchKernelGGL(gemm_mfma, grid, blk, 0, stream, X, Wt, bias, outb, PN, K, ostride, act);
  };
  auto GAT = [&](const int* rp, const int* cl, const float* dv, const __bf16* T, int tstr,
                 float* Acc, int n) {
    hipLaunchKernelGGL(gather_half, rgrid, blk, 0, stream, rp, cl, dv, T, tstr, 0,   Acc, n);
    hipLaunchKernelGGL(gather_half, rgrid, blk, 0, stream, rp, cl, dv, T, tstr, 128, Acc, n);
  };
  auto COMB = [&](const float* gb, const float* linb, const float* dv,
                  const float* AccSS, const float* icv,
                  const float* lw, const float* lb, __bf16* o, int ostr, int n, int act) {
    hipLaunchKernelGGL(combine_ln2, rgrid, blk, 0, stream, AccG, TL, 512, dv, gb, linb,
                       TL + 256, AccSS, icv, lw, lb, o, ostr, n, act);
  };

  // ---- converts ----
  {
    WPack p;
    const float* srcs[16] = { seq_init_W, gs1_gcn_W, gs1_lin_W, gs2_gcn_W, gs2_lin_W,
                              dd1_W, dr1_W, pp1_W, pr1_W, pp2_W, pr2_W,
                              dt1_W, td1_W, td2_W, seq_fc_W, skip_fc_W };
    __bf16* dsts[16] = { Wseq, pair0, pair0 + 65536, pair1, pair1 + 65536,
                         pair2, pair2 + 65536, pair3, pair3 + 65536, pair4, pair4 + 65536,
                         Wdt1, Wtd1, Wtd2, Wsfc, Wskp };
    for (int i = 0; i < 16; ++i) { p.src[i] = srcs[i]; p.dst[i] = dsts[i]; p.n[i] = (i == 0) ? 256*1024 : 256*256; }
    hipLaunchKernelGGL(convert_weights, dim3(16, 16), blk, 0, stream, p);
  }
  {
    EPack p;
    p.src[0] = seq;      p.dst[0] = Eseq; p.n[0] = PN * SEQK;
    p.src[1] = drug_emb; p.dst[1] = Ed;   p.n[1] = PN * 256;
    p.src[2] = prot_emb; p.dst[2] = Ep;   p.n[2] = PN * 256;
    hipLaunchKernelGGL(convert_emb, dim3(2048, 3), blk, 0, stream, p);
  }

  // ---- counting-sort CSR build (no global atomics) ----
  GPack g;
  g.src[0] = ppi;        g.dst[0] = ppi + EPPI; g.nE[0] = EPPI;
  g.src[1] = ddi;        g.dst[1] = ddi + EDDI; g.nE[1] = EDDI;
  g.src[2] = dti + EDTI; g.dst[2] = dti;        g.nE[2] = EDTI;
  g.src[3] = dti;        g.dst[3] = dti + EDTI; g.nE[3] = EDTI;
  g.col[0] = colP;  g.col[1] = colD;  g.col[2] = colTD;  g.col[3] = colTP;
  g.rowptr[0] = rowptrP; g.rowptr[1] = rowptrD; g.rowptr[2] = rowptrTD; g.rowptr[3] = rowptrTP;
  g.outdeg[0] = dinvP; g.outdeg[1] = dinvD; g.outdeg[2] = icD; g.outdeg[3] = icP;
  g.stg[0] = stgP; g.stg[1] = stgD; g.stg[2] = stgTD; g.stg[3] = stgTP;
  g.bh = bh; g.bbase = bbase;

  hipLaunchKernelGGL(sort_hist,    sgrid, blk, 0, stream, g);
  hipLaunchKernelGGL(sort_scan,    dim3(1, 4), dim3(1024), 0, stream, g);
  hipLaunchKernelGGL(sort_scatter, sgrid, blk, 0, stream, g);
  hipLaunchKernelGGL(bucket_csr,   bgrid, blk, 0, stream, g);

  // ---- pair sort by idx1 bucket ----
  hipLaunchKernelGGL(psort_hist,    dim3(NPBLK), blk, 0, stream, idx1, ph);
  hipLaunchKernelGGL(psort_scan,    dim3(1), dim3(1024), 0, stream, ph);
  hipLaunchKernelGGL(psort_scatter, dim3(NPBLK), blk, 0, stream, idx1, idx2, ph, pstg);

  // ---- P1: x_seq = relu(Eseq @ Wseq^T) -> B0 ----
  GEMM(Eseq, Wseq, nullptr, B0, SEQK, 256, 1, g256);

  // ---- P2 (gs1): h -> B2 ----
  GEMM(B0, pair0, nullptr, TL, 256, 512, 0, g512);
  GAT(rowptrP, colP, dinvP, TL, 512, AccG, PN);
  COMB(gs1_gcn_b, nullptr, dinvP, nullptr, nullptr, gs1_ln_w, gs1_ln_b, B2, 256, PN, 1);

  // ---- P3 (gs2): x1 -> PK slot0 (Eseq dead from here) ----
  GEMM(B2, pair1, nullptr, TL, 256, 512, 0, g512);
  GAT(rowptrP, colP, dinvP, TL, 512, AccG, PN);
  COMB(gs2_gcn_b, nullptr, dinvP, nullptr, nullptr, gs2_ln_w, gs2_ln_b, PK + 0, 1024, PN, 0);

  // ---- P4d (drug layer 1): d -> B2 ----
  GEMM(Ed, pair2, nullptr, TL, 256, 512, 0, g512);         // dd1 | dr1
  GEMM(Ep, Wdt1, dt1_b, B4, 256, 256, 0, g256);            // proj_p
  GAT(rowptrD, colD, dinvD, TL, 512, AccG, DN);
  GAT(rowptrTD, colTD, nullptr, B4, 256, AccS, DN);
  COMB(dd1_b, dr1_b, dinvD, AccS, icD, nullptr, nullptr, B2, 256, DN, 1);

  // ---- P4p (protein layer 1): p -> B5 ----
  GEMM(Ep, pair3, nullptr, TL, 256, 512, 0, g512);         // pp1 | pr1
  GEMM(Ed, Wtd1, td1_b, B4, 256, 256, 0, g256);            // proj_d
  GAT(rowptrP, colP, dinvP, TL, 512, AccG, PN);
  GAT(rowptrTP, colTP, nullptr, B4, 256, AccS, PN);
  COMB(pp1_b, pr1_b, dinvP, AccS, icP, nullptr, nullptr, B5, 256, PN, 1);

  // ---- P5 (protein layer 2): p2 -> PK slot2 ----
  GEMM(B2, Wtd2, td2_b, B4, 256, 256, 0, g256);            // proj (td2) from d
  GEMM(B5, pair4, nullptr, TL, 256, 512, 0, g512);         // pp2 | pr2 from p
  GAT(rowptrP, colP, dinvP, TL, 512, AccG, PN);
  GAT(rowptrTP, colTP, nullptr, B4, 256, AccS, PN);
  COMB(pp2_b, pr2_b, dinvP, AccS, icP, nullptr, nullptr, PK + 512, 1024, PN, 0);

  // ---- P6: fuse precompute ----
  hipLaunchKernelGGL(ln_elu, rgrid, blk, 0, stream, B0, B4, PN);  // fp
  GEMM(B4, Wsfc, nullptr, PK + 256, 256, 1024, 2, g256);          // x_fp -> slot1
  GEMM(Ep, Wskp, nullptr, PK + 768, 256, 1024, 0, g256);          // x_skip -> slot3

  // ---- P7: pair epilogue over sorted pairs ----
  hipLaunchKernelGGL(pair_kernel, dim3((NPAIRN + 3) / 4), blk, 0, stream,
                     PK, pstg, wR, wI, outp, NPAIRN);
}

// Round 9
// 930.587 us; speedup vs baseline: 1.1744x; 1.1744x over previous
//
#include <hip/hip_runtime.h>
#include <hip/hip_bf16.h>
#include <math.h>

#define PN 20000
#define DN 20000
#define SEQK 1024
#define EPPI 640000
#define EDDI 640000
#define EDTI 400000
#define NPAIRN 100000
#define RPB 128            // rows per bucket
#define NBUCK 157          // ceil(20000/128)
#define CH 4096            // edges per sort block
#define NBLKMAX 157        // ceil(640000/4096)
#define RBX 40             // row-blocks per XCD = ceil(313/8)

typedef float4 f4;
using bf16x8 = __attribute__((ext_vector_type(8))) __bf16;
using bf16x4 = __attribute__((ext_vector_type(4))) __bf16;
using f32x4v = __attribute__((ext_vector_type(4))) float;

__device__ __forceinline__ f4 ld4(const float* p) { return *reinterpret_cast<const f4*>(p); }
__device__ __forceinline__ f4 ldb4(const __bf16* p) {
  bf16x4 v = *reinterpret_cast<const bf16x4*>(p);
  return make_float4((float)v[0], (float)v[1], (float)v[2], (float)v[3]);
}
__device__ __forceinline__ void stb4(__bf16* p, f4 v) {
  bf16x4 o;
  o[0] = (__bf16)v.x; o[1] = (__bf16)v.y; o[2] = (__bf16)v.z; o[3] = (__bf16)v.w;
  *reinterpret_cast<bf16x4*>(p) = o;
}
__device__ __forceinline__ void acc4(f4& a, f4 b) { a.x+=b.x; a.y+=b.y; a.z+=b.z; a.w+=b.w; }
__device__ __forceinline__ void acc4s(f4& a, f4 b, float s) { a.x+=s*b.x; a.y+=s*b.y; a.z+=s*b.z; a.w+=s*b.w; }

__device__ __forceinline__ void wave_ln(f4& x) {
  float s  = x.x + x.y + x.z + x.w;
  float ss = x.x*x.x + x.y*x.y + x.z*x.z + x.w*x.w;
#pragma unroll
  for (int o = 32; o; o >>= 1) { s += __shfl_xor(s, o, 64); ss += __shfl_xor(ss, o, 64); }
  float m = s * (1.f/256.f);
  float v = ss * (1.f/256.f) - m*m;
  float r = rsqrtf(v + 1e-5f);
  x.x = (x.x-m)*r; x.y = (x.y-m)*r; x.z = (x.z-m)*r; x.w = (x.w-m)*r;
}

__device__ __forceinline__ bf16x8 cvt8(const float* p) {
  f4 u = ld4(p), v = ld4(p + 4);
  bf16x8 r;
  r[0] = (__bf16)u.x; r[1] = (__bf16)u.y; r[2] = (__bf16)u.z; r[3] = (__bf16)u.w;
  r[4] = (__bf16)v.x; r[5] = (__bf16)v.y; r[6] = (__bf16)v.z; r[7] = (__bf16)v.w;
  return r;
}

// ---------------- fp32 -> bf16 converters ----------------
struct WPack { const float* src[16]; __bf16* dst[16]; int n[16]; };
__global__ __launch_bounds__(256) void convert_weights(WPack p) {
  const int wi = blockIdx.y;
  const int n = p.n[wi];
  const float* s = p.src[wi];
  __bf16* d = p.dst[wi];
  for (int i = (blockIdx.x * 256 + threadIdx.x) * 4; i < n; i += gridDim.x * 256 * 4) {
    f4 v = ld4(s + i);
    stb4(d + i, v);
  }
}

struct EPack { const float* src[2]; __bf16* dst[2]; int n[2]; };
__global__ __launch_bounds__(256) void convert_emb(EPack p) {
  const int wi = blockIdx.y;
  const int n = p.n[wi];
  const float* s = p.src[wi];
  __bf16* d = p.dst[wi];
  for (int i = (blockIdx.x * 256 + threadIdx.x) * 4; i < n; i += gridDim.x * 256 * 4) {
    f4 v = ld4(s + i);
    stb4(d + i, v);
  }
}

// ---------------- MFMA GEMM, XCD-swizzled 1D grid ----------------
// bid -> xcd = bid&7, j = bid>>3; row_blk = xcd*RBX + j/ncol; col_blk = j%ncol.
// All col-blocks of a row-block run on the same XCD back-to-back: X fetched once/XCD.
__global__ __launch_bounds__(256) void gemm_mfma(
    const float* __restrict__ Xf, const __bf16* __restrict__ Xb,
    const __bf16* __restrict__ Wt, const float* __restrict__ bias,
    __bf16* __restrict__ outb, int M, int K, int ostride, int act, int ncol)
{
  const int bid = blockIdx.x;
  const int xcd = bid & 7;
  const int j = bid >> 3;
  const int row_blk = xcd * RBX + j / ncol;
  const int col_blk = j % ncol;
  if (row_blk * 64 >= M) return;

  const int tid = threadIdx.x;
  const int lane = tid & 63;
  const int w = tid >> 6;
  const int r0 = row_blk * 64 + (w >> 1) * 32;
  const int c0 = col_blk * 64 + (w & 1) * 32;
  const int l15 = lane & 15;
  const int lk = (lane >> 4) * 8;

  f32x4v acc[2][2];
#pragma unroll
  for (int m = 0; m < 2; ++m)
#pragma unroll
    for (int n = 0; n < 2; ++n) { acc[m][n][0]=0.f; acc[m][n][1]=0.f; acc[m][n][2]=0.f; acc[m][n][3]=0.f; }

  int ra = min(r0 + l15, M - 1);
  int rb = min(r0 + 16 + l15, M - 1);
  const float*  xfa = Xf ? Xf + (size_t)ra * K + lk : nullptr;
  const float*  xfb = Xf ? Xf + (size_t)rb * K + lk : nullptr;
  const __bf16* xba = Xb ? Xb + (size_t)ra * K + lk : nullptr;
  const __bf16* xbb = Xb ? Xb + (size_t)rb * K + lk : nullptr;
  const __bf16* wa = Wt + (size_t)(c0 + l15) * K + lk;
  const __bf16* wc = Wt + (size_t)(c0 + 16 + l15) * K + lk;

  for (int k0 = 0; k0 < K; k0 += 32) {
    bf16x8 a0, a1;
    if (Xb) {
      a0 = *reinterpret_cast<const bf16x8*>(xba + k0);
      a1 = *reinterpret_cast<const bf16x8*>(xbb + k0);
    } else {
      a0 = cvt8(xfa + k0);
      a1 = cvt8(xfb + k0);
    }
    bf16x8 b0 = *reinterpret_cast<const bf16x8*>(wa + k0);
    bf16x8 b1 = *reinterpret_cast<const bf16x8*>(wc + k0);
    acc[0][0] = __builtin_amdgcn_mfma_f32_16x16x32_bf16(a0, b0, acc[0][0], 0, 0, 0);
    acc[0][1] = __builtin_amdgcn_mfma_f32_16x16x32_bf16(a0, b1, acc[0][1], 0, 0, 0);
    acc[1][0] = __builtin_amdgcn_mfma_f32_16x16x32_bf16(a1, b0, acc[1][0], 0, 0, 0);
    acc[1][1] = __builtin_amdgcn_mfma_f32_16x16x32_bf16(a1, b1, acc[1][1], 0, 0, 0);
  }

  const int rowbase = r0 + (lane >> 4) * 4;
#pragma unroll
  for (int m = 0; m < 2; ++m) {
#pragma unroll
    for (int i = 0; i < 4; ++i) {
      int row = rowbase + m * 16 + i;
      if (row >= M) continue;
#pragma unroll
      for (int n2 = 0; n2 < 2; ++n2) {
        int col = c0 + n2 * 16 + l15;
        float v = acc[m][n2][i];
        if (bias) v += bias[col];
        if (act == 1) v = fmaxf(v, 0.f);
        else if (act == 2) v = v > 0.f ? v : (expf(v) - 1.f);
        outb[(size_t)row * ostride + col] = (__bf16)v;
      }
    }
  }
}

// ---------------- contention-free two-level counting-sort CSR build ----------------
struct GPack {
  const int* src[4]; const int* dst[4]; int nE[4];
  int* col[4]; int* rowptr[4]; float* outdeg[4];  // dinvP,dinvD,icD,icP
  unsigned* stg[4];
  int* bh;      // [4][NBUCK][NBLKMAX]
  int* bbase;   // [4][NBUCK+1]
};

__global__ __launch_bounds__(256) void sort_hist(GPack g) {
  __shared__ int h[NBUCK];
  const int gi = blockIdx.y, blk = blockIdx.x;
  const int t = threadIdx.x;
  for (int i = t; i < NBUCK; i += 256) h[i] = 0;
  __syncthreads();
  const int base = blk * CH, nE = g.nE[gi];
  const int* dst = g.dst[gi];
#pragma unroll
  for (int i = 0; i < CH / 256; ++i) {
    int e = base + i * 256 + t;
    if (e < nE) atomicAdd(&h[dst[e] >> 7], 1);
  }
  __syncthreads();
  int* bh = g.bh + (size_t)gi * NBUCK * NBLKMAX;
  for (int i = t; i < NBUCK; i += 256) bh[i * NBLKMAX + blk] = h[i];
}

__global__ __launch_bounds__(1024) void sort_scan(GPack g) {
  __shared__ int sums[1024];
  const int gi = blockIdx.y;
  int* bh = g.bh + (size_t)gi * NBUCK * NBLKMAX;
  int* bbase = g.bbase + gi * (NBUCK + 1);
  const int L = NBUCK * NBLKMAX;
  const int t = threadIdx.x;
  const int chunk = (L + 1023) / 1024;
  const int b = t * chunk;
  const int e = min(b + chunk, L);
  int s = 0;
  for (int i = b; i < e; ++i) s += bh[i];
  sums[t] = s;
  __syncthreads();
  for (int o = 1; o < 1024; o <<= 1) {
    int u = (t >= o) ? sums[t - o] : 0;
    __syncthreads();
    sums[t] += u;
    __syncthreads();
  }
  int run = sums[t] - s;
  for (int i = b; i < e; ++i) {
    if (i % NBLKMAX == 0) bbase[i / NBLKMAX] = run;
    int old = bh[i];
    bh[i] = run;
    run += old;
  }
  if (t == 0) bbase[NBUCK] = g.nE[gi];
}

__global__ __launch_bounds__(256) void sort_scatter(GPack g) {
  __shared__ int cur[NBUCK];
  const int gi = blockIdx.y, blk = blockIdx.x;
  const int t = threadIdx.x;
  const int* bh = g.bh + (size_t)gi * NBUCK * NBLKMAX;
  for (int i = t; i < NBUCK; i += 256) cur[i] = bh[i * NBLKMAX + blk];
  __syncthreads();
  const int base = blk * CH, nE = g.nE[gi];
  const int* src = g.src[gi];
  const int* dst = g.dst[gi];
  unsigned* stg = g.stg[gi];
#pragma unroll
  for (int i = 0; i < CH / 256; ++i) {
    int e = base + i * 256 + t;
    if (e < nE) {
      int d = dst[e];
      int bkt = d >> 7;
      int pos = atomicAdd(&cur[bkt], 1);
      stg[pos] = ((unsigned)src[e] << 7) | (unsigned)(d & 127);
    }
  }
}

__global__ __launch_bounds__(256) void bucket_csr(GPack g) {
  const int gi = blockIdx.y;
  const int b = blockIdx.x;
  const int base = g.bbase[gi * (NBUCK + 1) + b];
  const int cnt  = g.bbase[gi * (NBUCK + 1) + b + 1] - base;
  __shared__ int h[RPB], sc[RPB];
  const int t = threadIdx.x;
  if (t < RPB) h[t] = 0;
  __syncthreads();
  const unsigned* st = g.stg[gi] + base;
  const int row0 = b * RPB;
  for (int i = t; i < cnt; i += 256) atomicAdd(&h[st[i] & 127u], 1);
  __syncthreads();
  if (t == 0) { int run = 0; for (int r = 0; r < RPB; ++r) { sc[r] = run; run += h[r]; } }
  __syncthreads();
  const int rows = min(RPB, PN - row0);
  if (t < rows) {
    g.rowptr[gi][row0 + t] = base + sc[t];
    float c = (float)h[t];
    g.outdeg[gi][row0 + t] = (gi < 2) ? rsqrtf(c + 1.f) : (1.f / fmaxf(c, 1.f));
  }
  if (b == 0 && t == 0) g.rowptr[gi][PN] = g.nE[gi];
  __syncthreads();
  if (t < RPB) h[t] = sc[t];
  __syncthreads();
  for (int i = t; i < cnt; i += 256) {
    unsigned v = st[i];
    int pos = atomicAdd(&h[v & 127u], 1);
    g.col[gi][base + pos] = (int)(v >> 7);
  }
}

// ---------------- fused GCN stage (8-deep edge unroll) ----------------
__global__ __launch_bounds__(256) void gcn_combine(
    const int* __restrict__ rpG, const int* __restrict__ clG,
    const float* __restrict__ dinv,
    const __bf16* __restrict__ T, int tstride,
    const float* __restrict__ gb, const float* __restrict__ linb,
    const __bf16* __restrict__ L,
    const int* __restrict__ rpS, const int* __restrict__ clS,
    const float* __restrict__ ic, const __bf16* __restrict__ Pt,
    const float* __restrict__ lw, const float* __restrict__ lb,
    __bf16* __restrict__ out, int ostride, int n, int act)
{
  int row = (blockIdx.x * blockDim.x + threadIdx.x) >> 6;
  if (row >= n) return;
  int lane = threadIdx.x & 63;
  int o = lane * 4;
  float dd = dinv[row];

  f4 x = make_float4(0.f, 0.f, 0.f, 0.f);
  acc4s(x, ldb4(T + (size_t)row * tstride + o), dd * dd);   // self loop

  int beg = rpG[row], end = rpG[row + 1];
  int j = beg;
  for (; j + 7 < end; j += 8) {
    int s[8];
    float nn[8];
    f4 tv[8];
#pragma unroll
    for (int q = 0; q < 8; ++q) s[q] = clG[j + q];
#pragma unroll
    for (int q = 0; q < 8; ++q) nn[q] = dd * dinv[s[q]];
#pragma unroll
    for (int q = 0; q < 8; ++q) tv[q] = ldb4(T + (size_t)s[q] * tstride + o);
#pragma unroll
    for (int q = 0; q < 8; ++q) acc4s(x, tv[q], nn[q]);
  }
  for (; j < end; ++j) {
    int s0 = clG[j];
    acc4s(x, ldb4(T + (size_t)s0 * tstride + o), dd * dinv[s0]);
  }

  if (gb)   acc4(x, ld4(gb + o));
  if (linb) acc4(x, ld4(linb + o));
  if (L)    acc4(x, ldb4(L + (size_t)row * tstride + o));

  if (rpS) {
    f4 s4 = make_float4(0.f, 0.f, 0.f, 0.f);
    int sb = rpS[row], se = rpS[row + 1];
    int k = sb;
    for (; k + 7 < se; k += 8) {
      int s[8];
      f4 tv[8];
#pragma unroll
      for (int q = 0; q < 8; ++q) s[q] = clS[k + q];
#pragma unroll
      for (int q = 0; q < 8; ++q) tv[q] = ldb4(Pt + (size_t)s[q] * 256 + o);
#pragma unroll
      for (int q = 0; q < 8; ++q) acc4(s4, tv[q]);
    }
    for (; k < se; ++k) acc4(s4, ldb4(Pt + (size_t)clS[k] * 256 + o));
    acc4s(x, s4, ic[row]);
  }

  wave_ln(x);
  if (lw) {
    f4 w = ld4(lw + o), b = ld4(lb + o);
    x.x = x.x*w.x + b.x; x.y = x.y*w.y + b.y; x.z = x.z*w.z + b.z; x.w = x.w*w.w + b.w;
  }
  if (act == 1) {
    x.x = fmaxf(x.x, 0.f); x.y = fmaxf(x.y, 0.f); x.z = fmaxf(x.z, 0.f); x.w = fmaxf(x.w, 0.f);
  }
  stb4(out + (size_t)row * ostride + o, x);
}

// ---------------- fp = elu(LN(x_seq)) ----------------
__global__ __launch_bounds__(256) void ln_elu(const __bf16* __restrict__ in, __bf16* __restrict__ out, int n) {
  int row = (blockIdx.x * blockDim.x + threadIdx.x) >> 6;
  if (row >= n) return;
  int lane = threadIdx.x & 63;
  int o = lane * 4;
  f4 x = ldb4(in + (size_t)row * 256 + o);
  wave_ln(x);
  x.x = x.x > 0.f ? x.x : expf(x.x)-1.f;
  x.y = x.y > 0.f ? x.y : expf(x.y)-1.f;
  x.z = x.z > 0.f ? x.z : expf(x.z)-1.f;
  x.w = x.w > 0.f ? x.w : expf(x.w)-1.f;
  stb4(out + (size_t)row * 256 + o, x);
}

// ---------------- pair epilogue: PK interleaved [node][slot0..3][256] ----------------
__global__ __launch_bounds__(256) void pair_kernel(
    const __bf16* __restrict__ PK,
    const int* __restrict__ idx1, const int* __restrict__ idx2,
    const float* __restrict__ wR, const float* __restrict__ wI,
    float* __restrict__ out, int npair)
{
  int wid = (blockIdx.x * blockDim.x + threadIdx.x) >> 6;
  if (wid >= npair) return;
  int lane = threadIdx.x & 63;
  int f = lane * 4;
  const __bf16* r1 = PK + (size_t)idx1[wid] * 1024;
  const __bf16* r2 = PK + (size_t)idx2[wid] * 1024;

  f4 R1 = ldb4(r1 + f);        acc4(R1, ldb4(r2 + 256 + f)); wave_ln(R1);
  f4 I1 = ldb4(r1 + 512 + f);  acc4(I1, ldb4(r2 + 768 + f)); wave_ln(I1);
  f4 R2 = ldb4(r1 + 768 + f);  acc4(R2, ldb4(r2 + 512 + f)); wave_ln(R2);
  f4 I2 = ldb4(r1 + 256 + f);  acc4(I2, ldb4(r2 + f));       wave_ln(I2);

  f4 R, I;
  R.x = R1.x*R2.x - I1.x*I2.x;  I.x = R1.x*I2.x + I1.x*R2.x;
  R.y = R1.y*R2.y - I1.y*I2.y;  I.y = R1.y*I2.y + I1.y*R2.y;
  R.z = R1.z*R2.z - I1.z*I2.z;  I.z = R1.z*I2.z + I1.z*R2.z;
  R.w = R1.w*R2.w - I1.w*I2.w;  I.w = R1.w*I2.w + I1.w*R2.w;
  wave_ln(R); wave_ln(I);

  // r_+i_ = R.(wR-wI) + I.(wR+wI)
  f4 wr = ld4(wR + f), wi = ld4(wI + f);
  f4 wa = make_float4(wr.x-wi.x, wr.y-wi.y, wr.z-wi.z, wr.w-wi.w);
  f4 wb = make_float4(wr.x+wi.x, wr.y+wi.y, wr.z+wi.z, wr.w+wi.w);
  float t = R.x*wa.x + I.x*wb.x + R.y*wa.y + I.y*wb.y
          + R.z*wa.z + I.z*wb.z + R.w*wa.w + I.w*wb.w;
#pragma unroll
  for (int o = 32; o; o >>= 1) t += __shfl_xor(t, o, 64);
  if (lane == 0) out[wid] = 1.f / (1.f + expf(-t));
}

extern "C" void kernel_launch(void* const* d_in, const int* in_sizes, int n_in,
                              void* d_out, int out_size, void* d_ws, size_t ws_size,
                              hipStream_t stream) {
  (void)in_sizes; (void)n_in; (void)out_size; (void)ws_size;
  const float* seq        = (const float*)d_in[0];
  const int*   ppi        = (const int*)d_in[1];
  const int*   ddi        = (const int*)d_in[2];
  const int*   dti        = (const int*)d_in[3];
  const int*   idx1       = (const int*)d_in[4];
  const int*   idx2       = (const int*)d_in[5];
  const float* seq_init_W = (const float*)d_in[6];
  const float* gs1_gcn_W  = (const float*)d_in[7];
  const float* gs1_gcn_b  = (const float*)d_in[8];
  const float* gs1_lin_W  = (const float*)d_in[9];
  const float* gs1_ln_w   = (const float*)d_in[10];
  const float* gs1_ln_b   = (const float*)d_in[11];
  const float* gs2_gcn_W  = (const float*)d_in[12];
  const float* gs2_gcn_b  = (const float*)d_in[13];
  const float* gs2_lin_W  = (const float*)d_in[14];
  const float* gs2_ln_w   = (const float*)d_in[15];
  const float* gs2_ln_b   = (const float*)d_in[16];
  const float* drug_emb   = (const float*)d_in[17];
  const float* prot_emb   = (const float*)d_in[18];
  const float* pp1_W = (const float*)d_in[19]; const float* pp1_b = (const float*)d_in[20];
  const float* td1_W = (const float*)d_in[21]; const float* td1_b = (const float*)d_in[22];
  const float* pr1_W = (const float*)d_in[23]; const float* pr1_b = (const float*)d_in[24];
  const float* dd1_W = (const float*)d_in[25]; const float* dd1_b = (const float*)d_in[26];
  const float* dt1_W = (const float*)d_in[27]; const float* dt1_b = (const float*)d_in[28];
  const float* dr1_W = (const float*)d_in[29]; const float* dr1_b = (const float*)d_in[30];
  const float* pp2_W = (const float*)d_in[31]; const float* pp2_b = (const float*)d_in[32];
  const float* td2_W = (const float*)d_in[33]; const float* td2_b = (const float*)d_in[34];
  const float* pr2_W = (const float*)d_in[35]; const float* pr2_b = (const float*)d_in[36];
  const float* seq_fc_W  = (const float*)d_in[43];
  const float* skip_fc_W = (const float*)d_in[44];
  const float* wR = (const float*)d_in[45];
  const float* wI = (const float*)d_in[46];
  float* outp = (float*)d_out;

  // ---------------- workspace layout ----------------
  char* base = (char*)d_ws;
  unsigned* stgP  = (unsigned*)base;                 // EPPI
  unsigned* stgD  = stgP + EPPI;
  unsigned* stgTD = stgD + EDDI;
  unsigned* stgTP = stgTD + EDTI;
  int* colP  = (int*)(stgTP + EDTI);
  int* colD  = colP + EPPI;
  int* colTD = colD + EDDI;
  int* colTP = colTD + EDTI;
  int* rowptrP  = colTP + EDTI;
  int* rowptrD  = rowptrP + PN + 1;
  int* rowptrTD = rowptrD + PN + 1;
  int* rowptrTP = rowptrTD + PN + 1;
  float* dinvP = (float*)(rowptrTP + PN + 1);
  float* dinvD = dinvP + PN;
  float* icD   = dinvD + PN;
  float* icP   = icD + PN;
  int* bh    = (int*)(icP + PN);                     // 4*NBUCK*NBLKMAX
  int* bbase = bh + 4 * NBUCK * NBLKMAX;             // 4*(NBUCK+1)

  unsigned long long waddr = (unsigned long long)(bbase + 4 * (NBUCK + 1));
  waddr = (waddr + 63ULL) & ~63ULL;
  __bf16* wb = (__bf16*)waddr;
  __bf16* Wseq  = wb;                           // [256,1024]
  __bf16* pair0 = Wseq + 256*1024;              // each pair [512,256]
  __bf16* pair1 = pair0 + 512*256;
  __bf16* pair2 = pair1 + 512*256;
  __bf16* pair3 = pair2 + 512*256;
  __bf16* pair4 = pair3 + 512*256;
  __bf16* sing  = pair4 + 512*256;
  __bf16* Wdt1  = sing;
  __bf16* Wtd1  = sing + 65536;
  __bf16* Wtd2  = sing + 2*65536;
  __bf16* Wsfc  = sing + 3*65536;
  __bf16* Wskp  = sing + 4*65536;
  const size_t NB = (size_t)PN * 256;
  __bf16* Ed    = sing + 5*65536;               // [20000,256]
  __bf16* Ep    = Ed + NB;
  __bf16* TL    = Ep + NB;                      // [20000,512]
  __bf16* B0    = TL + (size_t)PN*512;          // x_seq
  __bf16* B2    = B0 + NB;                      // h -> d
  __bf16* B4    = B2 + NB;                      // proj -> fp
  __bf16* B5    = B4 + NB;                      // p
  __bf16* PK    = B5 + NB;                      // [20000][1024]: x1 | xfp | p2 | xskip

  const dim3 blk(256);
  const dim3 rgrid((PN + 3) / 4);
  const dim3 sgrid(NBLKMAX, 4);
  const dim3 bgrid(NBUCK, 4);

  auto GEMM = [&](const float* Xf, const __bf16* Xb, const __bf16* Wt, const float* bias,
                  __bf16* outb, int K, int ostride, int act, int ncol) {
    hipLaunchKernelGGL(gemm_mfma, dim3(8 * RBX * ncol), blk, 0, stream,
                       Xf, Xb, Wt, bias, outb, PN, K, ostride, act, ncol);
  };
  auto STAGE = [&](const int* rpG, const int* clG, const float* dv,
                   const float* gb, const float* linb,
                   const int* rpS, const int* clS, const float* ic, const __bf16* Pt,
                   const float* lw, const float* lb, __bf16* o, int ostr, int n, int act) {
    hipLaunchKernelGGL(gcn_combine, rgrid, blk, 0, stream, rpG, clG, dv, TL, 512, gb, linb,
                       TL + 256, rpS, clS, ic, Pt, lw, lb, o, ostr, n, act);
  };

  // ---- converts ----
  {
    WPack p;
    const float* srcs[16] = { seq_init_W, gs1_gcn_W, gs1_lin_W, gs2_gcn_W, gs2_lin_W,
                              dd1_W, dr1_W, pp1_W, pr1_W, pp2_W, pr2_W,
                              dt1_W, td1_W, td2_W, seq_fc_W, skip_fc_W };
    __bf16* dsts[16] = { Wseq, pair0, pair0 + 65536, pair1, pair1 + 65536,
                         pair2, pair2 + 65536, pair3, pair3 + 65536, pair4, pair4 + 65536,
                         Wdt1, Wtd1, Wtd2, Wsfc, Wskp };
    for (int i = 0; i < 16; ++i) { p.src[i] = srcs[i]; p.dst[i] = dsts[i]; p.n[i] = (i == 0) ? 256*1024 : 256*256; }
    hipLaunchKernelGGL(convert_weights, dim3(16, 16), blk, 0, stream, p);
  }
  {
    EPack p;
    p.src[0] = drug_emb; p.dst[0] = Ed; p.n[0] = PN * 256;
    p.src[1] = prot_emb; p.dst[1] = Ep; p.n[1] = PN * 256;
    hipLaunchKernelGGL(convert_emb, dim3(2048, 2), blk, 0, stream, p);
  }

  // ---- counting-sort CSR build (no global atomics) ----
  GPack g;
  g.src[0] = ppi;        g.dst[0] = ppi + EPPI; g.nE[0] = EPPI;
  g.src[1] = ddi;        g.dst[1] = ddi + EDDI; g.nE[1] = EDDI;
  g.src[2] = dti + EDTI; g.dst[2] = dti;        g.nE[2] = EDTI;
  g.src[3] = dti;        g.dst[3] = dti + EDTI; g.nE[3] = EDTI;
  g.col[0] = colP;  g.col[1] = colD;  g.col[2] = colTD;  g.col[3] = colTP;
  g.rowptr[0] = rowptrP; g.rowptr[1] = rowptrD; g.rowptr[2] = rowptrTD; g.rowptr[3] = rowptrTP;
  g.outdeg[0] = dinvP; g.outdeg[1] = dinvD; g.outdeg[2] = icD; g.outdeg[3] = icP;
  g.stg[0] = stgP; g.stg[1] = stgD; g.stg[2] = stgTD; g.stg[3] = stgTP;
  g.bh = bh; g.bbase = bbase;

  hipLaunchKernelGGL(sort_hist,    sgrid, blk, 0, stream, g);
  hipLaunchKernelGGL(sort_scan,    dim3(1, 4), dim3(1024), 0, stream, g);
  hipLaunchKernelGGL(sort_scatter, sgrid, blk, 0, stream, g);
  hipLaunchKernelGGL(bucket_csr,   bgrid, blk, 0, stream, g);

  // ---- P1: x_seq = relu(seq @ Wseq^T) -> B0 (fp32 A converted in-kernel) ----
  GEMM(seq, nullptr, Wseq, nullptr, B0, SEQK, 256, 1, 4);

  // ---- P2 (gs1): h -> B2 ----
  GEMM(nullptr, B0, pair0, nullptr, TL, 256, 512, 0, 8);
  STAGE(rowptrP, colP, dinvP, gs1_gcn_b, nullptr, nullptr, nullptr, nullptr, nullptr,
        gs1_ln_w, gs1_ln_b, B2, 256, PN, 1);

  // ---- P3 (gs2): x1 -> PK slot0 ----
  GEMM(nullptr, B2, pair1, nullptr, TL, 256, 512, 0, 8);
  STAGE(rowptrP, colP, dinvP, gs2_gcn_b, nullptr, nullptr, nullptr, nullptr, nullptr,
        gs2_ln_w, gs2_ln_b, PK + 0, 1024, PN, 0);

  // ---- P4d (drug layer 1): d -> B2 ----
  GEMM(nullptr, Ed, pair2, nullptr, TL, 256, 512, 0, 8);   // dd1 | dr1
  GEMM(nullptr, Ep, Wdt1, dt1_b, B4, 256, 256, 0, 4);      // proj_p
  STAGE(rowptrD, colD, dinvD, dd1_b, dr1_b, rowptrTD, colTD, icD, B4,
        nullptr, nullptr, B2, 256, DN, 1);

  // ---- P4p (protein layer 1): p -> B5 ----
  GEMM(nullptr, Ep, pair3, nullptr, TL, 256, 512, 0, 8);   // pp1 | pr1
  GEMM(nullptr, Ed, Wtd1, td1_b, B4, 256, 256, 0, 4);      // proj_d
  STAGE(rowptrP, colP, dinvP, pp1_b, pr1_b, rowptrTP, colTP, icP, B4,
        nullptr, nullptr, B5, 256, PN, 1);

  // ---- P5 (protein layer 2): p2 -> PK slot2 ----
  GEMM(nullptr, B2, Wtd2, td2_b, B4, 256, 256, 0, 4);      // proj (td2) from d
  GEMM(nullptr, B5, pair4, nullptr, TL, 256, 512, 0, 8);   // pp2 | pr2 from p
  STAGE(rowptrP, colP, dinvP, pp2_b, pr2_b, rowptrTP, colTP, icP, B4,
        nullptr, nullptr, PK + 512, 1024, PN, 0);

  // ---- P6: fuse precompute ----
  hipLaunchKernelGGL(ln_elu, rgrid, blk, 0, stream, B0, B4, PN);  // fp
  GEMM(nullptr, B4, Wsfc, nullptr, PK + 256, 256, 1024, 2, 4);    // x_fp -> slot1
  GEMM(nullptr, Ep, Wskp, nullptr, PK + 768, 256, 1024, 0, 4);    // x_skip -> slot3

  // ---- P7: pair epilogue ----
  hipLaunchKernelGGL(pair_kernel, dim3((NPAIRN + 3) / 4), blk, 0, stream,
                     PK, idx1, idx2, wR, wI, outp, NPAIRN);
}

// Round 10
// 910.514 us; speedup vs baseline: 1.2003x; 1.0220x over previous
//
#include <hip/hip_runtime.h>
#include <hip/hip_bf16.h>
#include <math.h>

#define PN 20000
#define DN 20000
#define SEQK 1024
#define EPPI 640000
#define EDDI 640000
#define EDTI 400000
#define NPAIRN 100000
#define RPB 128            // rows per bucket
#define NBUCK 157          // ceil(20000/128)
#define CH 4096            // edges per sort block
#define NBLKMAX 157        // ceil(640000/4096)
#define RBX 40             // row-blocks per XCD = ceil(313/8)

typedef float4 f4;
using bf16x8 = __attribute__((ext_vector_type(8))) __bf16;
using bf16x4 = __attribute__((ext_vector_type(4))) __bf16;
using f32x4v = __attribute__((ext_vector_type(4))) float;

__device__ __forceinline__ f4 ld4(const float* p) { return *reinterpret_cast<const f4*>(p); }
__device__ __forceinline__ f4 ldb4(const __bf16* p) {
  bf16x4 v = *reinterpret_cast<const bf16x4*>(p);
  return make_float4((float)v[0], (float)v[1], (float)v[2], (float)v[3]);
}
__device__ __forceinline__ void stb4(__bf16* p, f4 v) {
  bf16x4 o;
  o[0] = (__bf16)v.x; o[1] = (__bf16)v.y; o[2] = (__bf16)v.z; o[3] = (__bf16)v.w;
  *reinterpret_cast<bf16x4*>(p) = o;
}
__device__ __forceinline__ void acc4(f4& a, f4 b) { a.x+=b.x; a.y+=b.y; a.z+=b.z; a.w+=b.w; }
__device__ __forceinline__ void acc4s(f4& a, f4 b, float s) { a.x+=s*b.x; a.y+=s*b.y; a.z+=s*b.z; a.w+=s*b.w; }

__device__ __forceinline__ void wave_ln(f4& x) {
  float s  = x.x + x.y + x.z + x.w;
  float ss = x.x*x.x + x.y*x.y + x.z*x.z + x.w*x.w;
#pragma unroll
  for (int o = 32; o; o >>= 1) { s += __shfl_xor(s, o, 64); ss += __shfl_xor(ss, o, 64); }
  float m = s * (1.f/256.f);
  float v = ss * (1.f/256.f) - m*m;
  float r = rsqrtf(v + 1e-5f);
  x.x = (x.x-m)*r; x.y = (x.y-m)*r; x.z = (x.z-m)*r; x.w = (x.w-m)*r;
}

__device__ __forceinline__ bf16x8 cvt8(const float* p) {
  f4 u = ld4(p), v = ld4(p + 4);
  bf16x8 r;
  r[0] = (__bf16)u.x; r[1] = (__bf16)u.y; r[2] = (__bf16)u.z; r[3] = (__bf16)u.w;
  r[4] = (__bf16)v.x; r[5] = (__bf16)v.y; r[6] = (__bf16)v.z; r[7] = (__bf16)v.w;
  return r;
}

// ---------------- fp32 -> bf16 converters ----------------
struct WPack { const float* src[16]; __bf16* dst[16]; int n[16]; };
__global__ __launch_bounds__(256) void convert_weights(WPack p) {
  const int wi = blockIdx.y;
  const int n = p.n[wi];
  const float* s = p.src[wi];
  __bf16* d = p.dst[wi];
  for (int i = (blockIdx.x * 256 + threadIdx.x) * 4; i < n; i += gridDim.x * 256 * 4) {
    f4 v = ld4(s + i);
    stb4(d + i, v);
  }
}

struct EPack { const float* src[3]; __bf16* dst[3]; int n[3]; };
__global__ __launch_bounds__(256) void convert_emb(EPack p) {
  const int wi = blockIdx.y;
  const int n = p.n[wi];
  const float* s = p.src[wi];
  __bf16* d = p.dst[wi];
  for (int i = (blockIdx.x * 256 + threadIdx.x) * 4; i < n; i += gridDim.x * 256 * 4) {
    f4 v = ld4(s + i);
    stb4(d + i, v);
  }
}

// ---------------- MFMA GEMM, XCD-swizzled 1D grid ----------------
// bid -> xcd = bid&7, j = bid>>3; row_blk = xcd*RBX + j/ncol; col_blk = j%ncol.
// All col-blocks of a row-block run on the same XCD back-to-back: X fetched once/XCD.
__global__ __launch_bounds__(256) void gemm_mfma(
    const float* __restrict__ Xf, const __bf16* __restrict__ Xb,
    const __bf16* __restrict__ Wt, const float* __restrict__ bias,
    __bf16* __restrict__ outb, int M, int K, int ostride, int act, int ncol)
{
  const int bid = blockIdx.x;
  const int xcd = bid & 7;
  const int j = bid >> 3;
  const int row_blk = xcd * RBX + j / ncol;
  const int col_blk = j % ncol;
  if (row_blk * 64 >= M) return;

  const int tid = threadIdx.x;
  const int lane = tid & 63;
  const int w = tid >> 6;
  const int r0 = row_blk * 64 + (w >> 1) * 32;
  const int c0 = col_blk * 64 + (w & 1) * 32;
  const int l15 = lane & 15;
  const int lk = (lane >> 4) * 8;

  f32x4v acc[2][2];
#pragma unroll
  for (int m = 0; m < 2; ++m)
#pragma unroll
    for (int n = 0; n < 2; ++n) { acc[m][n][0]=0.f; acc[m][n][1]=0.f; acc[m][n][2]=0.f; acc[m][n][3]=0.f; }

  int ra = min(r0 + l15, M - 1);
  int rb = min(r0 + 16 + l15, M - 1);
  const float*  xfa = Xf ? Xf + (size_t)ra * K + lk : nullptr;
  const float*  xfb = Xf ? Xf + (size_t)rb * K + lk : nullptr;
  const __bf16* xba = Xb ? Xb + (size_t)ra * K + lk : nullptr;
  const __bf16* xbb = Xb ? Xb + (size_t)rb * K + lk : nullptr;
  const __bf16* wa = Wt + (size_t)(c0 + l15) * K + lk;
  const __bf16* wc = Wt + (size_t)(c0 + 16 + l15) * K + lk;

  for (int k0 = 0; k0 < K; k0 += 32) {
    bf16x8 a0, a1;
    if (Xb) {
      a0 = *reinterpret_cast<const bf16x8*>(xba + k0);
      a1 = *reinterpret_cast<const bf16x8*>(xbb + k0);
    } else {
      a0 = cvt8(xfa + k0);
      a1 = cvt8(xfb + k0);
    }
    bf16x8 b0 = *reinterpret_cast<const bf16x8*>(wa + k0);
    bf16x8 b1 = *reinterpret_cast<const bf16x8*>(wc + k0);
    acc[0][0] = __builtin_amdgcn_mfma_f32_16x16x32_bf16(a0, b0, acc[0][0], 0, 0, 0);
    acc[0][1] = __builtin_amdgcn_mfma_f32_16x16x32_bf16(a0, b1, acc[0][1], 0, 0, 0);
    acc[1][0] = __builtin_amdgcn_mfma_f32_16x16x32_bf16(a1, b0, acc[1][0], 0, 0, 0);
    acc[1][1] = __builtin_amdgcn_mfma_f32_16x16x32_bf16(a1, b1, acc[1][1], 0, 0, 0);
  }

  const int rowbase = r0 + (lane >> 4) * 4;
#pragma unroll
  for (int m = 0; m < 2; ++m) {
#pragma unroll
    for (int i = 0; i < 4; ++i) {
      int row = rowbase + m * 16 + i;
      if (row >= M) continue;
#pragma unroll
      for (int n2 = 0; n2 < 2; ++n2) {
        int col = c0 + n2 * 16 + l15;
        float v = acc[m][n2][i];
        if (bias) v += bias[col];
        if (act == 1) v = fmaxf(v, 0.f);
        else if (act == 2) v = v > 0.f ? v : (expf(v) - 1.f);
        outb[(size_t)row * ostride + col] = (__bf16)v;
      }
    }
  }
}

// ---------------- contention-free two-level counting-sort CSR build ----------------
struct GPack {
  const int* src[4]; const int* dst[4]; int nE[4];
  int* col[4]; int* rowptr[4]; float* outdeg[4];  // dinvP,dinvD,icD,icP
  unsigned* stg[4];
  int* bh;      // [4][NBUCK][NBLKMAX]
  int* bbase;   // [4][NBUCK+1]
};

__global__ __launch_bounds__(256) void sort_hist(GPack g) {
  __shared__ int h[NBUCK];
  const int gi = blockIdx.y, blk = blockIdx.x;
  const int t = threadIdx.x;
  for (int i = t; i < NBUCK; i += 256) h[i] = 0;
  __syncthreads();
  const int base = blk * CH, nE = g.nE[gi];
  const int* dst = g.dst[gi];
#pragma unroll
  for (int i = 0; i < CH / 256; ++i) {
    int e = base + i * 256 + t;
    if (e < nE) atomicAdd(&h[dst[e] >> 7], 1);
  }
  __syncthreads();
  int* bh = g.bh + (size_t)gi * NBUCK * NBLKMAX;
  for (int i = t; i < NBUCK; i += 256) bh[i * NBLKMAX + blk] = h[i];
}

__global__ __launch_bounds__(1024) void sort_scan(GPack g) {
  __shared__ int sums[1024];
  const int gi = blockIdx.y;
  int* bh = g.bh + (size_t)gi * NBUCK * NBLKMAX;
  int* bbase = g.bbase + gi * (NBUCK + 1);
  const int L = NBUCK * NBLKMAX;
  const int t = threadIdx.x;
  const int chunk = (L + 1023) / 1024;
  const int b = t * chunk;
  const int e = min(b + chunk, L);
  int s = 0;
  for (int i = b; i < e; ++i) s += bh[i];
  sums[t] = s;
  __syncthreads();
  for (int o = 1; o < 1024; o <<= 1) {
    int u = (t >= o) ? sums[t - o] : 0;
    __syncthreads();
    sums[t] += u;
    __syncthreads();
  }
  int run = sums[t] - s;
  for (int i = b; i < e; ++i) {
    if (i % NBLKMAX == 0) bbase[i / NBLKMAX] = run;
    int old = bh[i];
    bh[i] = run;
    run += old;
  }
  if (t == 0) bbase[NBUCK] = g.nE[gi];
}

__global__ __launch_bounds__(256) void sort_scatter(GPack g) {
  __shared__ int cur[NBUCK];
  const int gi = blockIdx.y, blk = blockIdx.x;
  const int t = threadIdx.x;
  const int* bh = g.bh + (size_t)gi * NBUCK * NBLKMAX;
  for (int i = t; i < NBUCK; i += 256) cur[i] = bh[i * NBLKMAX + blk];
  __syncthreads();
  const int base = blk * CH, nE = g.nE[gi];
  const int* src = g.src[gi];
  const int* dst = g.dst[gi];
  unsigned* stg = g.stg[gi];
#pragma unroll
  for (int i = 0; i < CH / 256; ++i) {
    int e = base + i * 256 + t;
    if (e < nE) {
      int d = dst[e];
      int bkt = d >> 7;
      int pos = atomicAdd(&cur[bkt], 1);
      stg[pos] = ((unsigned)src[e] << 7) | (unsigned)(d & 127);
    }
  }
}

__global__ __launch_bounds__(256) void bucket_csr(GPack g) {
  const int gi = blockIdx.y;
  const int b = blockIdx.x;
  const int base = g.bbase[gi * (NBUCK + 1) + b];
  const int cnt  = g.bbase[gi * (NBUCK + 1) + b + 1] - base;
  __shared__ int h[RPB], sc[RPB];
  const int t = threadIdx.x;
  if (t < RPB) h[t] = 0;
  __syncthreads();
  const unsigned* st = g.stg[gi] + base;
  const int row0 = b * RPB;
  for (int i = t; i < cnt; i += 256) atomicAdd(&h[st[i] & 127u], 1);
  __syncthreads();
  if (t == 0) { int run = 0; for (int r = 0; r < RPB; ++r) { sc[r] = run; run += h[r]; } }
  __syncthreads();
  const int rows = min(RPB, PN - row0);
  if (t < rows) {
    g.rowptr[gi][row0 + t] = base + sc[t];
    float c = (float)h[t];
    g.outdeg[gi][row0 + t] = (gi < 2) ? rsqrtf(c + 1.f) : (1.f / fmaxf(c, 1.f));
  }
  if (b == 0 && t == 0) g.rowptr[gi][PN] = g.nE[gi];
  __syncthreads();
  if (t < RPB) h[t] = sc[t];
  __syncthreads();
  for (int i = t; i < cnt; i += 256) {
    unsigned v = st[i];
    int pos = atomicAdd(&h[v & 127u], 1);
    g.col[gi][base + pos] = (int)(v >> 7);
  }
}

// ---------------- fused GCN stage (8-deep edge unroll) ----------------
__global__ __launch_bounds__(256) void gcn_combine(
    const int* __restrict__ rpG, const int* __restrict__ clG,
    const float* __restrict__ dinv,
    const __bf16* __restrict__ T, int tstride,
    const float* __restrict__ gb, const float* __restrict__ linb,
    const __bf16* __restrict__ L,
    const int* __restrict__ rpS, const int* __restrict__ clS,
    const float* __restrict__ ic, const __bf16* __restrict__ Pt,
    const float* __restrict__ lw, const float* __restrict__ lb,
    __bf16* __restrict__ out, int ostride, int n, int act)
{
  int row = (blockIdx.x * blockDim.x + threadIdx.x) >> 6;
  if (row >= n) return;
  int lane = threadIdx.x & 63;
  int o = lane * 4;
  float dd = dinv[row];

  f4 x = make_float4(0.f, 0.f, 0.f, 0.f);
  acc4s(x, ldb4(T + (size_t)row * tstride + o), dd * dd);   // self loop

  int beg = rpG[row], end = rpG[row + 1];
  int j = beg;
  for (; j + 7 < end; j += 8) {
    int s[8];
    float nn[8];
    f4 tv[8];
#pragma unroll
    for (int q = 0; q < 8; ++q) s[q] = clG[j + q];
#pragma unroll
    for (int q = 0; q < 8; ++q) nn[q] = dd * dinv[s[q]];
#pragma unroll
    for (int q = 0; q < 8; ++q) tv[q] = ldb4(T + (size_t)s[q] * tstride + o);
#pragma unroll
    for (int q = 0; q < 8; ++q) acc4s(x, tv[q], nn[q]);
  }
  for (; j < end; ++j) {
    int s0 = clG[j];
    acc4s(x, ldb4(T + (size_t)s0 * tstride + o), dd * dinv[s0]);
  }

  if (gb)   acc4(x, ld4(gb + o));
  if (linb) acc4(x, ld4(linb + o));
  if (L)    acc4(x, ldb4(L + (size_t)row * tstride + o));

  if (rpS) {
    f4 s4 = make_float4(0.f, 0.f, 0.f, 0.f);
    int sb = rpS[row], se = rpS[row + 1];
    int k = sb;
    for (; k + 7 < se; k += 8) {
      int s[8];
      f4 tv[8];
#pragma unroll
      for (int q = 0; q < 8; ++q) s[q] = clS[k + q];
#pragma unroll
      for (int q = 0; q < 8; ++q) tv[q] = ldb4(Pt + (size_t)s[q] * 256 + o);
#pragma unroll
      for (int q = 0; q < 8; ++q) acc4(s4, tv[q]);
    }
    for (; k < se; ++k) acc4(s4, ldb4(Pt + (size_t)clS[k] * 256 + o));
    acc4s(x, s4, ic[row]);
  }

  wave_ln(x);
  if (lw) {
    f4 w = ld4(lw + o), b = ld4(lb + o);
    x.x = x.x*w.x + b.x; x.y = x.y*w.y + b.y; x.z = x.z*w.z + b.z; x.w = x.w*w.w + b.w;
  }
  if (act == 1) {
    x.x = fmaxf(x.x, 0.f); x.y = fmaxf(x.y, 0.f); x.z = fmaxf(x.z, 0.f); x.w = fmaxf(x.w, 0.f);
  }
  stb4(out + (size_t)row * ostride + o, x);
}

// ---------------- fp = elu(LN(x_seq)) ----------------
__global__ __launch_bounds__(256) void ln_elu(const __bf16* __restrict__ in, __bf16* __restrict__ out, int n) {
  int row = (blockIdx.x * blockDim.x + threadIdx.x) >> 6;
  if (row >= n) return;
  int lane = threadIdx.x & 63;
  int o = lane * 4;
  f4 x = ldb4(in + (size_t)row * 256 + o);
  wave_ln(x);
  x.x = x.x > 0.f ? x.x : expf(x.x)-1.f;
  x.y = x.y > 0.f ? x.y : expf(x.y)-1.f;
  x.z = x.z > 0.f ? x.z : expf(x.z)-1.f;
  x.w = x.w > 0.f ? x.w : expf(x.w)-1.f;
  stb4(out + (size_t)row * 256 + o, x);
}

// ---------------- pair epilogue: PK interleaved [node][slot0..3][256] ----------------
__global__ __launch_bounds__(256) void pair_kernel(
    const __bf16* __restrict__ PK,
    const int* __restrict__ idx1, const int* __restrict__ idx2,
    const float* __restrict__ wR, const float* __restrict__ wI,
    float* __restrict__ out, int npair)
{
  int wid = (blockIdx.x * blockDim.x + threadIdx.x) >> 6;
  if (wid >= npair) return;
  int lane = threadIdx.x & 63;
  int f = lane * 4;
  const __bf16* r1 = PK + (size_t)idx1[wid] * 1024;
  const __bf16* r2 = PK + (size_t)idx2[wid] * 1024;

  f4 R1 = ldb4(r1 + f);        acc4(R1, ldb4(r2 + 256 + f)); wave_ln(R1);
  f4 I1 = ldb4(r1 + 512 + f);  acc4(I1, ldb4(r2 + 768 + f)); wave_ln(I1);
  f4 R2 = ldb4(r1 + 768 + f);  acc4(R2, ldb4(r2 + 512 + f)); wave_ln(R2);
  f4 I2 = ldb4(r1 + 256 + f);  acc4(I2, ldb4(r2 + f));       wave_ln(I2);

  f4 R, I;
  R.x = R1.x*R2.x - I1.x*I2.x;  I.x = R1.x*I2.x + I1.x*R2.x;
  R.y = R1.y*R2.y - I1.y*I2.y;  I.y = R1.y*I2.y + I1.y*R2.y;
  R.z = R1.z*R2.z - I1.z*I2.z;  I.z = R1.z*I2.z + I1.z*R2.z;
  R.w = R1.w*R2.w - I1.w*I2.w;  I.w = R1.w*I2.w + I1.w*R2.w;
  wave_ln(R); wave_ln(I);

  // r_+i_ = R.(wR-wI) + I.(wR+wI)
  f4 wr = ld4(wR + f), wi = ld4(wI + f);
  f4 wa = make_float4(wr.x-wi.x, wr.y-wi.y, wr.z-wi.z, wr.w-wi.w);
  f4 wb = make_float4(wr.x+wi.x, wr.y+wi.y, wr.z+wi.z, wr.w+wi.w);
  float t = R.x*wa.x + I.x*wb.x + R.y*wa.y + I.y*wb.y
          + R.z*wa.z + I.z*wb.z + R.w*wa.w + I.w*wb.w;
#pragma unroll
  for (int o = 32; o; o >>= 1) t += __shfl_xor(t, o, 64);
  if (lane == 0) out[wid] = 1.f / (1.f + expf(-t));
}

extern "C" void kernel_launch(void* const* d_in, const int* in_sizes, int n_in,
                              void* d_out, int out_size, void* d_ws, size_t ws_size,
                              hipStream_t stream) {
  (void)in_sizes; (void)n_in; (void)out_size; (void)ws_size;
  const float* seq        = (const float*)d_in[0];
  const int*   ppi        = (const int*)d_in[1];
  const int*   ddi        = (const int*)d_in[2];
  const int*   dti        = (const int*)d_in[3];
  const int*   idx1       = (const int*)d_in[4];
  const int*   idx2       = (const int*)d_in[5];
  const float* seq_init_W = (const float*)d_in[6];
  const float* gs1_gcn_W  = (const float*)d_in[7];
  const float* gs1_gcn_b  = (const float*)d_in[8];
  const float* gs1_lin_W  = (const float*)d_in[9];
  const float* gs1_ln_w   = (const float*)d_in[10];
  const float* gs1_ln_b   = (const float*)d_in[11];
  const float* gs2_gcn_W  = (const float*)d_in[12];
  const float* gs2_gcn_b  = (const float*)d_in[13];
  const float* gs2_lin_W  = (const float*)d_in[14];
  const float* gs2_ln_w   = (const float*)d_in[15];
  const float* gs2_ln_b   = (const float*)d_in[16];
  const float* drug_emb   = (const float*)d_in[17];
  const float* prot_emb   = (const float*)d_in[18];
  const float* pp1_W = (const float*)d_in[19]; const float* pp1_b = (const float*)d_in[20];
  const float* td1_W = (const float*)d_in[21]; const float* td1_b = (const float*)d_in[22];
  const float* pr1_W = (const float*)d_in[23]; const float* pr1_b = (const float*)d_in[24];
  const float* dd1_W = (const float*)d_in[25]; const float* dd1_b = (const float*)d_in[26];
  const float* dt1_W = (const float*)d_in[27]; const float* dt1_b = (const float*)d_in[28];
  const float* dr1_W = (const float*)d_in[29]; const float* dr1_b = (const float*)d_in[30];
  const float* pp2_W = (const float*)d_in[31]; const float* pp2_b = (const float*)d_in[32];
  const float* td2_W = (const float*)d_in[33]; const float* td2_b = (const float*)d_in[34];
  const float* pr2_W = (const float*)d_in[35]; const float* pr2_b = (const float*)d_in[36];
  const float* seq_fc_W  = (const float*)d_in[43];
  const float* skip_fc_W = (const float*)d_in[44];
  const float* wR = (const float*)d_in[45];
  const float* wI = (const float*)d_in[46];
  float* outp = (float*)d_out;

  // ---------------- workspace layout ----------------
  char* base = (char*)d_ws;
  unsigned* stgP  = (unsigned*)base;                 // EPPI
  unsigned* stgD  = stgP + EPPI;
  unsigned* stgTD = stgD + EDDI;
  unsigned* stgTP = stgTD + EDTI;
  int* colP  = (int*)(stgTP + EDTI);
  int* colD  = colP + EPPI;
  int* colTD = colD + EDDI;
  int* colTP = colTD + EDTI;
  int* rowptrP  = colTP + EDTI;
  int* rowptrD  = rowptrP + PN + 1;
  int* rowptrTD = rowptrD + PN + 1;
  int* rowptrTP = rowptrTD + PN + 1;
  float* dinvP = (float*)(rowptrTP + PN + 1);
  float* dinvD = dinvP + PN;
  float* icD   = dinvD + PN;
  float* icP   = icD + PN;
  int* bh    = (int*)(icP + PN);                     // 4*NBUCK*NBLKMAX
  int* bbase = bh + 4 * NBUCK * NBLKMAX;             // 4*(NBUCK+1)

  unsigned long long waddr = (unsigned long long)(bbase + 4 * (NBUCK + 1));
  waddr = (waddr + 63ULL) & ~63ULL;
  __bf16* wb = (__bf16*)waddr;
  __bf16* Wseq  = wb;                           // [256,1024]
  __bf16* pair0 = Wseq + 256*1024;              // each pair [512,256]
  __bf16* pair1 = pair0 + 512*256;
  __bf16* pair2 = pair1 + 512*256;
  __bf16* pair3 = pair2 + 512*256;
  __bf16* pair4 = pair3 + 512*256;
  __bf16* sing  = pair4 + 512*256;
  __bf16* Wdt1  = sing;
  __bf16* Wtd1  = sing + 65536;
  __bf16* Wtd2  = sing + 2*65536;
  __bf16* Wsfc  = sing + 3*65536;
  __bf16* Wskp  = sing + 4*65536;
  const size_t NB = (size_t)PN * 256;
  __bf16* Ed    = sing + 5*65536;               // [20000,256]
  __bf16* Ep    = Ed + NB;
  __bf16* TL    = Ep + NB;                      // [20000,512]
  __bf16* B0    = TL + (size_t)PN*512;          // x_seq
  __bf16* B2    = B0 + NB;                      // h -> d
  __bf16* B4    = B2 + NB;                      // proj -> fp
  __bf16* B5    = B4 + NB;                      // p
  __bf16* PK    = B5 + NB;                      // [20000][1024]: x1 | xfp | p2 | xskip
  __bf16* Eseq  = PK;                           // alias: [20000,1024], dead after P1 (PK writes start at P3)

  const dim3 blk(256);
  const dim3 rgrid((PN + 3) / 4);
  const dim3 sgrid(NBLKMAX, 4);
  const dim3 bgrid(NBUCK, 4);

  auto GEMM = [&](const float* Xf, const __bf16* Xb, const __bf16* Wt, const float* bias,
                  __bf16* outb, int K, int ostride, int act, int ncol) {
    hipLaunchKernelGGL(gemm_mfma, dim3(8 * RBX * ncol), blk, 0, stream,
                       Xf, Xb, Wt, bias, outb, PN, K, ostride, act, ncol);
  };
  auto STAGE = [&](const int* rpG, const int* clG, const float* dv,
                   const float* gb, const float* linb,
                   const int* rpS, const int* clS, const float* ic, const __bf16* Pt,
                   const float* lw, const float* lb, __bf16* o, int ostr, int n, int act) {
    hipLaunchKernelGGL(gcn_combine, rgrid, blk, 0, stream, rpG, clG, dv, TL, 512, gb, linb,
                       TL + 256, rpS, clS, ic, Pt, lw, lb, o, ostr, n, act);
  };

  // ---- converts ----
  {
    WPack p;
    const float* srcs[16] = { seq_init_W, gs1_gcn_W, gs1_lin_W, gs2_gcn_W, gs2_lin_W,
                              dd1_W, dr1_W, pp1_W, pr1_W, pp2_W, pr2_W,
                              dt1_W, td1_W, td2_W, seq_fc_W, skip_fc_W };
    __bf16* dsts[16] = { Wseq, pair0, pair0 + 65536, pair1, pair1 + 65536,
                         pair2, pair2 + 65536, pair3, pair3 + 65536, pair4, pair4 + 65536,
                         Wdt1, Wtd1, Wtd2, Wsfc, Wskp };
    for (int i = 0; i < 16; ++i) { p.src[i] = srcs[i]; p.dst[i] = dsts[i]; p.n[i] = (i == 0) ? 256*1024 : 256*256; }
    hipLaunchKernelGGL(convert_weights, dim3(16, 16), blk, 0, stream, p);
  }
  {
    EPack p;
    p.src[0] = seq;      p.dst[0] = Eseq; p.n[0] = PN * SEQK;
    p.src[1] = drug_emb; p.dst[1] = Ed;   p.n[1] = PN * 256;
    p.src[2] = prot_emb; p.dst[2] = Ep;   p.n[2] = PN * 256;
    hipLaunchKernelGGL(convert_emb, dim3(2048, 3), blk, 0, stream, p);
  }

  // ---- counting-sort CSR build (no global atomics) ----
  GPack g;
  g.src[0] = ppi;        g.dst[0] = ppi + EPPI; g.nE[0] = EPPI;
  g.src[1] = ddi;        g.dst[1] = ddi + EDDI; g.nE[1] = EDDI;
  g.src[2] = dti + EDTI; g.dst[2] = dti;        g.nE[2] = EDTI;
  g.src[3] = dti;        g.dst[3] = dti + EDTI; g.nE[3] = EDTI;
  g.col[0] = colP;  g.col[1] = colD;  g.col[2] = colTD;  g.col[3] = colTP;
  g.rowptr[0] = rowptrP; g.rowptr[1] = rowptrD; g.rowptr[2] = rowptrTD; g.rowptr[3] = rowptrTP;
  g.outdeg[0] = dinvP; g.outdeg[1] = dinvD; g.outdeg[2] = icD; g.outdeg[3] = icP;
  g.stg[0] = stgP; g.stg[1] = stgD; g.stg[2] = stgTD; g.stg[3] = stgTP;
  g.bh = bh; g.bbase = bbase;

  hipLaunchKernelGGL(sort_hist,    sgrid, blk, 0, stream, g);
  hipLaunchKernelGGL(sort_scan,    dim3(1, 4), dim3(1024), 0, stream, g);
  hipLaunchKernelGGL(sort_scatter, sgrid, blk, 0, stream, g);
  hipLaunchKernelGGL(bucket_csr,   bgrid, blk, 0, stream, g);

  // ---- P1: x_seq = relu(Eseq @ Wseq^T) -> B0 (bf16 A, XCD-swizzled) ----
  GEMM(nullptr, Eseq, Wseq, nullptr, B0, SEQK, 256, 1, 4);

  // ---- P2 (gs1): h -> B2 ----
  GEMM(nullptr, B0, pair0, nullptr, TL, 256, 512, 0, 8);
  STAGE(rowptrP, colP, dinvP, gs1_gcn_b, nullptr, nullptr, nullptr, nullptr, nullptr,
        gs1_ln_w, gs1_ln_b, B2, 256, PN, 1);

  // ---- P3 (gs2): x1 -> PK slot0 (Eseq dead from here) ----
  GEMM(nullptr, B2, pair1, nullptr, TL, 256, 512, 0, 8);
  STAGE(rowptrP, colP, dinvP, gs2_gcn_b, nullptr, nullptr, nullptr, nullptr, nullptr,
        gs2_ln_w, gs2_ln_b, PK + 0, 1024, PN, 0);

  // ---- P4d (drug layer 1): d -> B2 ----
  GEMM(nullptr, Ed, pair2, nullptr, TL, 256, 512, 0, 8);   // dd1 | dr1
  GEMM(nullptr, Ep, Wdt1, dt1_b, B4, 256, 256, 0, 4);      // proj_p
  STAGE(rowptrD, colD, dinvD, dd1_b, dr1_b, rowptrTD, colTD, icD, B4,
        nullptr, nullptr, B2, 256, DN, 1);

  // ---- P4p (protein layer 1): p -> B5 ----
  GEMM(nullptr, Ep, pair3, nullptr, TL, 256, 512, 0, 8);   // pp1 | pr1
  GEMM(nullptr, Ed, Wtd1, td1_b, B4, 256, 256, 0, 4);      // proj_d
  STAGE(rowptrP, colP, dinvP, pp1_b, pr1_b, rowptrTP, colTP, icP, B4,
        nullptr, nullptr, B5, 256, PN, 1);

  // ---- P5 (protein layer 2): p2 -> PK slot2 ----
  GEMM(nullptr, B2, Wtd2, td2_b, B4, 256, 256, 0, 4);      // proj (td2) from d
  GEMM(nullptr, B5, pair4, nullptr, TL, 256, 512, 0, 8);   // pp2 | pr2 from p
  STAGE(rowptrP, colP, dinvP, pp2_b, pr2_b, rowptrTP, colTP, icP, B4,
        nullptr, nullptr, PK + 512, 1024, PN, 0);

  // ---- P6: fuse precompute ----
  hipLaunchKernelGGL(ln_elu, rgrid, blk, 0, stream, B0, B4, PN);  // fp
  GEMM(nullptr, B4, Wsfc, nullptr, PK + 256, 256, 1024, 2, 4);    // x_fp -> slot1
  GEMM(nullptr, Ep, Wskp, nullptr, PK + 768, 256, 1024, 0, 4);    // x_skip -> slot3

  // ---- P7: pair epilogue ----
  hipLaunchKernelGGL(pair_kernel, dim3((NPAIRN + 3) / 4), blk, 0, stream,
                     PK, idx1, idx2, wR, wI, outp, NPAIRN);
}

// Round 11
// 907.439 us; speedup vs baseline: 1.2044x; 1.0034x over previous
//
#include <hip/hip_runtime.h>
#include <hip/hip_bf16.h>
#include <math.h>

#define PN 20000
#define DN 20000
#define SEQK 1024
#define EPPI 640000
#define EDDI 640000
#define EDTI 400000
#define NPAIRN 100000
#define RPB 128            // rows per bucket
#define NBUCK 157          // ceil(20000/128)
#define CH 4096            // edges per sort block
#define NBLKMAX 157        // ceil(640000/4096)
#define RBX 40             // row-blocks per XCD = ceil(313/8)

typedef float4 f4;
using bf16x8 = __attribute__((ext_vector_type(8))) __bf16;
using bf16x4 = __attribute__((ext_vector_type(4))) __bf16;
using f32x4v = __attribute__((ext_vector_type(4))) float;

__device__ __forceinline__ f4 ld4(const float* p) { return *reinterpret_cast<const f4*>(p); }
__device__ __forceinline__ f4 ldb4(const __bf16* p) {
  bf16x4 v = *reinterpret_cast<const bf16x4*>(p);
  return make_float4((float)v[0], (float)v[1], (float)v[2], (float)v[3]);
}
__device__ __forceinline__ void stb4(__bf16* p, f4 v) {
  bf16x4 o;
  o[0] = (__bf16)v.x; o[1] = (__bf16)v.y; o[2] = (__bf16)v.z; o[3] = (__bf16)v.w;
  *reinterpret_cast<bf16x4*>(p) = o;
}
__device__ __forceinline__ void acc4(f4& a, f4 b) { a.x+=b.x; a.y+=b.y; a.z+=b.z; a.w+=b.w; }
__device__ __forceinline__ void acc4s(f4& a, f4 b, float s) { a.x+=s*b.x; a.y+=s*b.y; a.z+=s*b.z; a.w+=s*b.w; }

__device__ __forceinline__ void wave_ln(f4& x) {
  float s  = x.x + x.y + x.z + x.w;
  float ss = x.x*x.x + x.y*x.y + x.z*x.z + x.w*x.w;
#pragma unroll
  for (int o = 32; o; o >>= 1) { s += __shfl_xor(s, o, 64); ss += __shfl_xor(ss, o, 64); }
  float m = s * (1.f/256.f);
  float v = ss * (1.f/256.f) - m*m;
  float r = rsqrtf(v + 1e-5f);
  x.x = (x.x-m)*r; x.y = (x.y-m)*r; x.z = (x.z-m)*r; x.w = (x.w-m)*r;
}

// LN over 256 feats held as 8 floats/lane across a 32-lane half-wave.
__device__ __forceinline__ void ln8(float* v) {
  float s = 0.f, ss = 0.f;
#pragma unroll
  for (int i = 0; i < 8; ++i) { s += v[i]; ss += v[i]*v[i]; }
#pragma unroll
  for (int o = 16; o; o >>= 1) { s += __shfl_xor(s, o, 64); ss += __shfl_xor(ss, o, 64); }
  float m = s * (1.f/256.f);
  float var = ss * (1.f/256.f) - m*m;
  float r = rsqrtf(var + 1e-5f);
#pragma unroll
  for (int i = 0; i < 8; ++i) v[i] = (v[i]-m)*r;
}

// ---------------- fp32 -> bf16 converters ----------------
struct WPack { const float* src[16]; __bf16* dst[16]; int n[16]; };
__global__ __launch_bounds__(256) void convert_weights(WPack p) {
  const int wi = blockIdx.y;
  const int n = p.n[wi];
  const float* s = p.src[wi];
  __bf16* d = p.dst[wi];
  for (int i = (blockIdx.x * 256 + threadIdx.x) * 4; i < n; i += gridDim.x * 256 * 4) {
    f4 v = ld4(s + i);
    stb4(d + i, v);
  }
}

struct EPack { const float* src[3]; __bf16* dst[3]; int n[3]; };
__global__ __launch_bounds__(256) void convert_emb(EPack p) {
  const int wi = blockIdx.y;
  const int n = p.n[wi];
  const float* s = p.src[wi];
  __bf16* d = p.dst[wi];
  for (int i = (blockIdx.x * 256 + threadIdx.x) * 4; i < n; i += gridDim.x * 256 * 4) {
    f4 v = ld4(s + i);
    stb4(d + i, v);
  }
}

// ---------------- MFMA GEMM, XCD-swizzled 1D grid ----------------
// scale: if non-null, multiply output cols [0,256) by scale[row] (GCN dinv pre-fold).
__global__ __launch_bounds__(256) void gemm_mfma(
    const float* __restrict__ Xf, const __bf16* __restrict__ Xb,
    const __bf16* __restrict__ Wt, const float* __restrict__ bias,
    const float* __restrict__ scale,
    __bf16* __restrict__ outb, int M, int K, int ostride, int act, int ncol)
{
  const int bid = blockIdx.x;
  const int xcd = bid & 7;
  const int j = bid >> 3;
  const int row_blk = xcd * RBX + j / ncol;
  const int col_blk = j % ncol;
  if (row_blk * 64 >= M) return;

  const int tid = threadIdx.x;
  const int lane = tid & 63;
  const int w = tid >> 6;
  const int r0 = row_blk * 64 + (w >> 1) * 32;
  const int c0 = col_blk * 64 + (w & 1) * 32;
  const int l15 = lane & 15;
  const int lk = (lane >> 4) * 8;

  f32x4v acc[2][2];
#pragma unroll
  for (int m = 0; m < 2; ++m)
#pragma unroll
    for (int n = 0; n < 2; ++n) { acc[m][n][0]=0.f; acc[m][n][1]=0.f; acc[m][n][2]=0.f; acc[m][n][3]=0.f; }

  int ra = min(r0 + l15, M - 1);
  int rb = min(r0 + 16 + l15, M - 1);
  const float*  xfa = Xf ? Xf + (size_t)ra * K + lk : nullptr;
  const float*  xfb = Xf ? Xf + (size_t)rb * K + lk : nullptr;
  const __bf16* xba = Xb ? Xb + (size_t)ra * K + lk : nullptr;
  const __bf16* xbb = Xb ? Xb + (size_t)rb * K + lk : nullptr;
  const __bf16* wa = Wt + (size_t)(c0 + l15) * K + lk;
  const __bf16* wc = Wt + (size_t)(c0 + 16 + l15) * K + lk;

  for (int k0 = 0; k0 < K; k0 += 32) {
    bf16x8 a0, a1;
    if (Xb) {
      a0 = *reinterpret_cast<const bf16x8*>(xba + k0);
      a1 = *reinterpret_cast<const bf16x8*>(xbb + k0);
    } else {
      f4 u = ld4(xfa + k0), v = ld4(xfa + k0 + 4);
      a0[0]=(__bf16)u.x; a0[1]=(__bf16)u.y; a0[2]=(__bf16)u.z; a0[3]=(__bf16)u.w;
      a0[4]=(__bf16)v.x; a0[5]=(__bf16)v.y; a0[6]=(__bf16)v.z; a0[7]=(__bf16)v.w;
      u = ld4(xfb + k0); v = ld4(xfb + k0 + 4);
      a1[0]=(__bf16)u.x; a1[1]=(__bf16)u.y; a1[2]=(__bf16)u.z; a1[3]=(__bf16)u.w;
      a1[4]=(__bf16)v.x; a1[5]=(__bf16)v.y; a1[6]=(__bf16)v.z; a1[7]=(__bf16)v.w;
    }
    bf16x8 b0 = *reinterpret_cast<const bf16x8*>(wa + k0);
    bf16x8 b1 = *reinterpret_cast<const bf16x8*>(wc + k0);
    acc[0][0] = __builtin_amdgcn_mfma_f32_16x16x32_bf16(a0, b0, acc[0][0], 0, 0, 0);
    acc[0][1] = __builtin_amdgcn_mfma_f32_16x16x32_bf16(a0, b1, acc[0][1], 0, 0, 0);
    acc[1][0] = __builtin_amdgcn_mfma_f32_16x16x32_bf16(a1, b0, acc[1][0], 0, 0, 0);
    acc[1][1] = __builtin_amdgcn_mfma_f32_16x16x32_bf16(a1, b1, acc[1][1], 0, 0, 0);
  }

  const int rowbase = r0 + (lane >> 4) * 4;
#pragma unroll
  for (int m = 0; m < 2; ++m) {
#pragma unroll
    for (int i = 0; i < 4; ++i) {
      int row = rowbase + m * 16 + i;
      if (row >= M) continue;
#pragma unroll
      for (int n2 = 0; n2 < 2; ++n2) {
        int col = c0 + n2 * 16 + l15;
        float v = acc[m][n2][i];
        if (bias) v += bias[col];
        if (act == 1) v = fmaxf(v, 0.f);
        else if (act == 2) v = v > 0.f ? v : (expf(v) - 1.f);
        if (scale && col < 256) v *= scale[row];
        outb[(size_t)row * ostride + col] = (__bf16)v;
      }
    }
  }
}

// ---------------- contention-free two-level counting-sort CSR build ----------------
struct GPack {
  const int* src[4]; const int* dst[4]; int nE[4];
  int* col[4]; int* rowptr[4]; float* outdeg[4];  // dinvP,dinvD,icD,icP
  unsigned* stg[4];
  int* bh;      // [4][NBUCK][NBLKMAX]
  int* bbase;   // [4][NBUCK+1]
};

__global__ __launch_bounds__(256) void sort_hist(GPack g) {
  __shared__ int h[NBUCK];
  const int gi = blockIdx.y, blk = blockIdx.x;
  const int t = threadIdx.x;
  for (int i = t; i < NBUCK; i += 256) h[i] = 0;
  __syncthreads();
  const int base = blk * CH, nE = g.nE[gi];
  const int* dst = g.dst[gi];
#pragma unroll
  for (int i = 0; i < CH / 256; ++i) {
    int e = base + i * 256 + t;
    if (e < nE) atomicAdd(&h[dst[e] >> 7], 1);
  }
  __syncthreads();
  int* bh = g.bh + (size_t)gi * NBUCK * NBLKMAX;
  for (int i = t; i < NBUCK; i += 256) bh[i * NBLKMAX + blk] = h[i];
}

__global__ __launch_bounds__(1024) void sort_scan(GPack g) {
  __shared__ int sums[1024];
  const int gi = blockIdx.y;
  int* bh = g.bh + (size_t)gi * NBUCK * NBLKMAX;
  int* bbase = g.bbase + gi * (NBUCK + 1);
  const int L = NBUCK * NBLKMAX;
  const int t = threadIdx.x;
  const int chunk = (L + 1023) / 1024;
  const int b = t * chunk;
  const int e = min(b + chunk, L);
  int s = 0;
  for (int i = b; i < e; ++i) s += bh[i];
  sums[t] = s;
  __syncthreads();
  for (int o = 1; o < 1024; o <<= 1) {
    int u = (t >= o) ? sums[t - o] : 0;
    __syncthreads();
    sums[t] += u;
    __syncthreads();
  }
  int run = sums[t] - s;
  for (int i = b; i < e; ++i) {
    if (i % NBLKMAX == 0) bbase[i / NBLKMAX] = run;
    int old = bh[i];
    bh[i] = run;
    run += old;
  }
  if (t == 0) bbase[NBUCK] = g.nE[gi];
}

__global__ __launch_bounds__(256) void sort_scatter(GPack g) {
  __shared__ int cur[NBUCK];
  const int gi = blockIdx.y, blk = blockIdx.x;
  const int t = threadIdx.x;
  const int* bh = g.bh + (size_t)gi * NBUCK * NBLKMAX;
  for (int i = t; i < NBUCK; i += 256) cur[i] = bh[i * NBLKMAX + blk];
  __syncthreads();
  const int base = blk * CH, nE = g.nE[gi];
  const int* src = g.src[gi];
  const int* dst = g.dst[gi];
  unsigned* stg = g.stg[gi];
#pragma unroll
  for (int i = 0; i < CH / 256; ++i) {
    int e = base + i * 256 + t;
    if (e < nE) {
      int d = dst[e];
      int bkt = d >> 7;
      int pos = atomicAdd(&cur[bkt], 1);
      stg[pos] = ((unsigned)src[e] << 7) | (unsigned)(d & 127);
    }
  }
}

__global__ __launch_bounds__(256) void bucket_csr(GPack g) {
  const int gi = blockIdx.y;
  const int b = blockIdx.x;
  const int base = g.bbase[gi * (NBUCK + 1) + b];
  const int cnt  = g.bbase[gi * (NBUCK + 1) + b + 1] - base;
  __shared__ int h[RPB], sc[RPB];
  const int t = threadIdx.x;
  if (t < RPB) h[t] = 0;
  __syncthreads();
  const unsigned* st = g.stg[gi] + base;
  const int row0 = b * RPB;
  for (int i = t; i < cnt; i += 256) atomicAdd(&h[st[i] & 127u], 1);
  __syncthreads();
  if (t == 0) { int run = 0; for (int r = 0; r < RPB; ++r) { sc[r] = run; run += h[r]; } }
  __syncthreads();
  const int rows = min(RPB, PN - row0);
  if (t < rows) {
    g.rowptr[gi][row0 + t] = base + sc[t];
    float c = (float)h[t];
    g.outdeg[gi][row0 + t] = (gi < 2) ? rsqrtf(c + 1.f) : (1.f / fmaxf(c, 1.f));
  }
  if (b == 0 && t == 0) g.rowptr[gi][PN] = g.nE[gi];
  __syncthreads();
  if (t < RPB) h[t] = sc[t];
  __syncthreads();
  for (int i = t; i < cnt; i += 256) {
    unsigned v = st[i];
    int pos = atomicAdd(&h[v & 127u], 1);
    g.col[gi][base + pos] = (int)(v >> 7);
  }
}

// ---------------- fused GCN stage (8-deep edge unroll; T pre-scaled by dinv) ----------------
__global__ __launch_bounds__(256) void gcn_combine(
    const int* __restrict__ rpG, const int* __restrict__ clG,
    const float* __restrict__ dinv,
    const __bf16* __restrict__ T, int tstride,
    const float* __restrict__ gb, const float* __restrict__ linb,
    const __bf16* __restrict__ L,
    const int* __restrict__ rpS, const int* __restrict__ clS,
    const float* __restrict__ ic, const __bf16* __restrict__ Pt,
    const float* __restrict__ lw, const float* __restrict__ lb,
    __bf16* __restrict__ out, int ostride, int n, int act)
{
  int row = (blockIdx.x * blockDim.x + threadIdx.x) >> 6;
  if (row >= n) return;
  int lane = threadIdx.x & 63;
  int o = lane * 4;
  float dd = dinv[row];

  // gacc accumulates T' = dinv*T rows: self + neighbors; x = dd * gacc.
  f4 gacc = ldb4(T + (size_t)row * tstride + o);   // self loop (T' row)

  int beg = rpG[row], end = rpG[row + 1];
  int j = beg;
  for (; j + 7 < end; j += 8) {
    int s[8];
    f4 tv[8];
#pragma unroll
    for (int q = 0; q < 8; ++q) s[q] = clG[j + q];
#pragma unroll
    for (int q = 0; q < 8; ++q) tv[q] = ldb4(T + (size_t)s[q] * tstride + o);
#pragma unroll
    for (int q = 0; q < 8; ++q) acc4(gacc, tv[q]);
  }
  for (; j < end; ++j) {
    acc4(gacc, ldb4(T + (size_t)clG[j] * tstride + o));
  }

  f4 x = make_float4(0.f, 0.f, 0.f, 0.f);
  acc4s(x, gacc, dd);

  if (gb)   acc4(x, ld4(gb + o));
  if (linb) acc4(x, ld4(linb + o));
  if (L)    acc4(x, ldb4(L + (size_t)row * tstride + o));

  if (rpS) {
    f4 s4 = make_float4(0.f, 0.f, 0.f, 0.f);
    int sb = rpS[row], se = rpS[row + 1];
    int k = sb;
    for (; k + 7 < se; k += 8) {
      int s[8];
      f4 tv[8];
#pragma unroll
      for (int q = 0; q < 8; ++q) s[q] = clS[k + q];
#pragma unroll
      for (int q = 0; q < 8; ++q) tv[q] = ldb4(Pt + (size_t)s[q] * 256 + o);
#pragma unroll
      for (int q = 0; q < 8; ++q) acc4(s4, tv[q]);
    }
    for (; k < se; ++k) acc4(s4, ldb4(Pt + (size_t)clS[k] * 256 + o));
    acc4s(x, s4, ic[row]);
  }

  wave_ln(x);
  if (lw) {
    f4 w = ld4(lw + o), b = ld4(lb + o);
    x.x = x.x*w.x + b.x; x.y = x.y*w.y + b.y; x.z = x.z*w.z + b.z; x.w = x.w*w.w + b.w;
  }
  if (act == 1) {
    x.x = fmaxf(x.x, 0.f); x.y = fmaxf(x.y, 0.f); x.z = fmaxf(x.z, 0.f); x.w = fmaxf(x.w, 0.f);
  }
  stb4(out + (size_t)row * ostride + o, x);
}

// ---------------- fp = elu(LN(x_seq)) ----------------
__global__ __launch_bounds__(256) void ln_elu(const __bf16* __restrict__ in, __bf16* __restrict__ out, int n) {
  int row = (blockIdx.x * blockDim.x + threadIdx.x) >> 6;
  if (row >= n) return;
  int lane = threadIdx.x & 63;
  int o = lane * 4;
  f4 x = ldb4(in + (size_t)row * 256 + o);
  wave_ln(x);
  x.x = x.x > 0.f ? x.x : expf(x.x)-1.f;
  x.y = x.y > 0.f ? x.y : expf(x.y)-1.f;
  x.z = x.z > 0.f ? x.z : expf(x.z)-1.f;
  x.w = x.w > 0.f ? x.w : expf(x.w)-1.f;
  stb4(out + (size_t)row * 256 + o, x);
}

// ---------------- pair epilogue: one pair per 32-lane half-wave ----------------
// PK interleaved [node][slot0..3][256]: slot0=x1, slot1=xfp, slot2=p2, slot3=xskip
__global__ __launch_bounds__(256) void pair_kernel(
    const __bf16* __restrict__ PK,
    const int* __restrict__ idx1, const int* __restrict__ idx2,
    const float* __restrict__ wR, const float* __restrict__ wI,
    float* __restrict__ out, int npair)
{
  int pid = (blockIdx.x * 256 + threadIdx.x) >> 5;
  if (pid >= npair) return;
  int l = threadIdx.x & 31;
  int f = l * 8;
  const __bf16* r1 = PK + (size_t)idx1[pid] * 1024;
  const __bf16* r2 = PK + (size_t)idx2[pid] * 1024;

  // 8 independent 16B loads (max MLP)
  bf16x8 a0 = *reinterpret_cast<const bf16x8*>(r1 + f);         // x1[i1]
  bf16x8 a1 = *reinterpret_cast<const bf16x8*>(r1 + 256 + f);   // xfp[i1]
  bf16x8 a2 = *reinterpret_cast<const bf16x8*>(r1 + 512 + f);   // p2[i1]
  bf16x8 a3 = *reinterpret_cast<const bf16x8*>(r1 + 768 + f);   // xskip[i1]
  bf16x8 b0 = *reinterpret_cast<const bf16x8*>(r2 + f);         // x1[i2]
  bf16x8 b1 = *reinterpret_cast<const bf16x8*>(r2 + 256 + f);   // xfp[i2]
  bf16x8 b2 = *reinterpret_cast<const bf16x8*>(r2 + 512 + f);   // p2[i2]
  bf16x8 b3 = *reinterpret_cast<const bf16x8*>(r2 + 768 + f);   // xskip[i2]

  float R1[8], I1[8], R2[8], I2[8];
#pragma unroll
  for (int i = 0; i < 8; ++i) {
    R1[i] = (float)a0[i] + (float)b1[i];   // x1[i1] + xfp[i2]
    I1[i] = (float)a2[i] + (float)b3[i];   // p2[i1] + xskip[i2]
    R2[i] = (float)a3[i] + (float)b2[i];   // xskip[i1] + p2[i2]
    I2[i] = (float)a1[i] + (float)b0[i];   // xfp[i1] + x1[i2]
  }
  ln8(R1); ln8(I1); ln8(R2); ln8(I2);

  float R[8], I[8];
#pragma unroll
  for (int i = 0; i < 8; ++i) {
    R[i] = R1[i]*R2[i] - I1[i]*I2[i];
    I[i] = R1[i]*I2[i] + I1[i]*R2[i];
  }
  ln8(R); ln8(I);

  // r_+i_ = R.(wR-wI) + I.(wR+wI)
  f4 wr0 = ld4(wR + f), wr1 = ld4(wR + f + 4);
  f4 wi0 = ld4(wI + f), wi1 = ld4(wI + f + 4);
  float wrv[8] = {wr0.x,wr0.y,wr0.z,wr0.w, wr1.x,wr1.y,wr1.z,wr1.w};
  float wiv[8] = {wi0.x,wi0.y,wi0.z,wi0.w, wi1.x,wi1.y,wi1.z,wi1.w};
  float t = 0.f;
#pragma unroll
  for (int i = 0; i < 8; ++i) t += R[i]*(wrv[i]-wiv[i]) + I[i]*(wrv[i]+wiv[i]);
#pragma unroll
  for (int o = 16; o; o >>= 1) t += __shfl_xor(t, o, 64);
  if (l == 0) out[pid] = 1.f / (1.f + expf(-t));
}

extern "C" void kernel_launch(void* const* d_in, const int* in_sizes, int n_in,
                              void* d_out, int out_size, void* d_ws, size_t ws_size,
                              hipStream_t stream) {
  (void)in_sizes; (void)n_in; (void)out_size; (void)ws_size;
  const float* seq        = (const float*)d_in[0];
  const int*   ppi        = (const int*)d_in[1];
  const int*   ddi        = (const int*)d_in[2];
  const int*   dti        = (const int*)d_in[3];
  const int*   idx1       = (const int*)d_in[4];
  const int*   idx2       = (const int*)d_in[5];
  const float* seq_init_W = (const float*)d_in[6];
  const float* gs1_gcn_W  = (const float*)d_in[7];
  const float* gs1_gcn_b  = (const float*)d_in[8];
  const float* gs1_lin_W  = (const float*)d_in[9];
  const float* gs1_ln_w   = (const float*)d_in[10];
  const float* gs1_ln_b   = (const float*)d_in[11];
  const float* gs2_gcn_W  = (const float*)d_in[12];
  const float* gs2_gcn_b  = (const float*)d_in[13];
  const float* gs2_lin_W  = (const float*)d_in[14];
  const float* gs2_ln_w   = (const float*)d_in[15];
  const float* gs2_ln_b   = (const float*)d_in[16];
  const float* drug_emb   = (const float*)d_in[17];
  const float* prot_emb   = (const float*)d_in[18];
  const float* pp1_W = (const float*)d_in[19]; const float* pp1_b = (const float*)d_in[20];
  const float* td1_W = (const float*)d_in[21]; const float* td1_b = (const float*)d_in[22];
  const float* pr1_W = (const float*)d_in[23]; const float* pr1_b = (const float*)d_in[24];
  const float* dd1_W = (const float*)d_in[25]; const float* dd1_b = (const float*)d_in[26];
  const float* dt1_W = (const float*)d_in[27]; const float* dt1_b = (const float*)d_in[28];
  const float* dr1_W = (const float*)d_in[29]; const float* dr1_b = (const float*)d_in[30];
  const float* pp2_W = (const float*)d_in[31]; const float* pp2_b = (const float*)d_in[32];
  const float* td2_W = (const float*)d_in[33]; const float* td2_b = (const float*)d_in[34];
  const float* pr2_W = (const float*)d_in[35]; const float* pr2_b = (const float*)d_in[36];
  const float* seq_fc_W  = (const float*)d_in[43];
  const float* skip_fc_W = (const float*)d_in[44];
  const float* wR = (const float*)d_in[45];
  const float* wI = (const float*)d_in[46];
  float* outp = (float*)d_out;

  // ---------------- workspace layout ----------------
  char* base = (char*)d_ws;
  unsigned* stgP  = (unsigned*)base;                 // EPPI
  unsigned* stgD  = stgP + EPPI;
  unsigned* stgTD = stgD + EDDI;
  unsigned* stgTP = stgTD + EDTI;
  int* colP  = (int*)(stgTP + EDTI);
  int* colD  = colP + EPPI;
  int* colTD = colD + EDDI;
  int* colTP = colTD + EDTI;
  int* rowptrP  = colTP + EDTI;
  int* rowptrD  = rowptrP + PN + 1;
  int* rowptrTD = rowptrD + PN + 1;
  int* rowptrTP = rowptrTD + PN + 1;
  float* dinvP = (float*)(rowptrTP + PN + 1);
  float* dinvD = dinvP + PN;
  float* icD   = dinvD + PN;
  float* icP   = icD + PN;
  int* bh    = (int*)(icP + PN);                     // 4*NBUCK*NBLKMAX
  int* bbase = bh + 4 * NBUCK * NBLKMAX;             // 4*(NBUCK+1)

  unsigned long long waddr = (unsigned long long)(bbase + 4 * (NBUCK + 1));
  waddr = (waddr + 63ULL) & ~63ULL;
  __bf16* wb = (__bf16*)waddr;
  __bf16* Wseq  = wb;                           // [256,1024]
  __bf16* pair0 = Wseq + 256*1024;              // each pair [512,256]
  __bf16* pair1 = pair0 + 512*256;
  __bf16* pair2 = pair1 + 512*256;
  __bf16* pair3 = pair2 + 512*256;
  __bf16* pair4 = pair3 + 512*256;
  __bf16* sing  = pair4 + 512*256;
  __bf16* Wdt1  = sing;
  __bf16* Wtd1  = sing + 65536;
  __bf16* Wtd2  = sing + 2*65536;
  __bf16* Wsfc  = sing + 3*65536;
  __bf16* Wskp  = sing + 4*65536;
  const size_t NB = (size_t)PN * 256;
  __bf16* Ed    = sing + 5*65536;               // [20000,256]
  __bf16* Ep    = Ed + NB;
  __bf16* TL    = Ep + NB;                      // [20000,512]
  __bf16* B0    = TL + (size_t)PN*512;          // x_seq
  __bf16* B2    = B0 + NB;                      // h -> d
  __bf16* B4    = B2 + NB;                      // proj -> fp
  __bf16* B5    = B4 + NB;                      // p
  __bf16* PK    = B5 + NB;                      // [20000][1024]: x1 | xfp | p2 | xskip
  __bf16* Eseq  = PK;                           // alias: [20000,1024], dead after P1 (PK writes start at P3)

  const dim3 blk(256);
  const dim3 rgrid((PN + 3) / 4);
  const dim3 sgrid(NBLKMAX, 4);
  const dim3 bgrid(NBUCK, 4);

  auto GEMM = [&](const float* Xf, const __bf16* Xb, const __bf16* Wt, const float* bias,
                  const float* scale, __bf16* outb, int K, int ostride, int act, int ncol) {
    hipLaunchKernelGGL(gemm_mfma, dim3(8 * RBX * ncol), blk, 0, stream,
                       Xf, Xb, Wt, bias, scale, outb, PN, K, ostride, act, ncol);
  };
  auto STAGE = [&](const int* rpG, const int* clG, const float* dv,
                   const float* gb, const float* linb,
                   const int* rpS, const int* clS, const float* ic, const __bf16* Pt,
                   const float* lw, const float* lb, __bf16* o, int ostr, int n, int act) {
    hipLaunchKernelGGL(gcn_combine, rgrid, blk, 0, stream, rpG, clG, dv, TL, 512, gb, linb,
                       TL + 256, rpS, clS, ic, Pt, lw, lb, o, ostr, n, act);
  };

  // ---- converts ----
  {
    WPack p;
    const float* srcs[16] = { seq_init_W, gs1_gcn_W, gs1_lin_W, gs2_gcn_W, gs2_lin_W,
                              dd1_W, dr1_W, pp1_W, pr1_W, pp2_W, pr2_W,
                              dt1_W, td1_W, td2_W, seq_fc_W, skip_fc_W };
    __bf16* dsts[16] = { Wseq, pair0, pair0 + 65536, pair1, pair1 + 65536,
                         pair2, pair2 + 65536, pair3, pair3 + 65536, pair4, pair4 + 65536,
                         Wdt1, Wtd1, Wtd2, Wsfc, Wskp };
    for (int i = 0; i < 16; ++i) { p.src[i] = srcs[i]; p.dst[i] = dsts[i]; p.n[i] = (i == 0) ? 256*1024 : 256*256; }
    hipLaunchKernelGGL(convert_weights, dim3(16, 16), blk, 0, stream, p);
  }
  {
    EPack p;
    p.src[0] = seq;      p.dst[0] = Eseq; p.n[0] = PN * SEQK;
    p.src[1] = drug_emb; p.dst[1] = Ed;   p.n[1] = PN * 256;
    p.src[2] = prot_emb; p.dst[2] = Ep;   p.n[2] = PN * 256;
    hipLaunchKernelGGL(convert_emb, dim3(2048, 3), blk, 0, stream, p);
  }

  // ---- counting-sort CSR build (no global atomics) ----
  GPack g;
  g.src[0] = ppi;        g.dst[0] = ppi + EPPI; g.nE[0] = EPPI;
  g.src[1] = ddi;        g.dst[1] = ddi + EDDI; g.nE[1] = EDDI;
  g.src[2] = dti + EDTI; g.dst[2] = dti;        g.nE[2] = EDTI;
  g.src[3] = dti;        g.dst[3] = dti + EDTI; g.nE[3] = EDTI;
  g.col[0] = colP;  g.col[1] = colD;  g.col[2] = colTD;  g.col[3] = colTP;
  g.rowptr[0] = rowptrP; g.rowptr[1] = rowptrD; g.rowptr[2] = rowptrTD; g.rowptr[3] = rowptrTP;
  g.outdeg[0] = dinvP; g.outdeg[1] = dinvD; g.outdeg[2] = icD; g.outdeg[3] = icP;
  g.stg[0] = stgP; g.stg[1] = stgD; g.stg[2] = stgTD; g.stg[3] = stgTP;
  g.bh = bh; g.bbase = bbase;

  hipLaunchKernelGGL(sort_hist,    sgrid, blk, 0, stream, g);
  hipLaunchKernelGGL(sort_scan,    dim3(1, 4), dim3(1024), 0, stream, g);
  hipLaunchKernelGGL(sort_scatter, sgrid, blk, 0, stream, g);
  hipLaunchKernelGGL(bucket_csr,   bgrid, blk, 0, stream, g);

  // ---- P1: x_seq = relu(Eseq @ Wseq^T) -> B0 (bf16 A, XCD-swizzled) ----
  GEMM(nullptr, Eseq, Wseq, nullptr, nullptr, B0, SEQK, 256, 1, 4);

  // ---- P2 (gs1): h -> B2 (t-half pre-scaled by dinvP) ----
  GEMM(nullptr, B0, pair0, nullptr, dinvP, TL, 256, 512, 0, 8);
  STAGE(rowptrP, colP, dinvP, gs1_gcn_b, nullptr, nullptr, nullptr, nullptr, nullptr,
        gs1_ln_w, gs1_ln_b, B2, 256, PN, 1);

  // ---- P3 (gs2): x1 -> PK slot0 (Eseq dead from here) ----
  GEMM(nullptr, B2, pair1, nullptr, dinvP, TL, 256, 512, 0, 8);
  STAGE(rowptrP, colP, dinvP, gs2_gcn_b, nullptr, nullptr, nullptr, nullptr, nullptr,
        gs2_ln_w, gs2_ln_b, PK + 0, 1024, PN, 0);

  // ---- P4d (drug layer 1): d -> B2 ----
  GEMM(nullptr, Ed, pair2, nullptr, dinvD, TL, 256, 512, 0, 8);   // dd1 | dr1
  GEMM(nullptr, Ep, Wdt1, dt1_b, nullptr, B4, 256, 256, 0, 4);    // proj_p
  STAGE(rowptrD, colD, dinvD, dd1_b, dr1_b, rowptrTD, colTD, icD, B4,
        nullptr, nullptr, B2, 256, DN, 1);

  // ---- P4p (protein layer 1): p -> B5 ----
  GEMM(nullptr, Ep, pair3, nullptr, dinvP, TL, 256, 512, 0, 8);   // pp1 | pr1
  GEMM(nullptr, Ed, Wtd1, td1_b, nullptr, B4, 256, 256, 0, 4);    // proj_d
  STAGE(rowptrP, colP, dinvP, pp1_b, pr1_b, rowptrTP, colTP, icP, B4,
        nullptr, nullptr, B5, 256, PN, 1);

  // ---- P5 (protein layer 2): p2 -> PK slot2 ----
  GEMM(nullptr, B2, Wtd2, td2_b, nullptr, B4, 256, 256, 0, 4);    // proj (td2) from d
  GEMM(nullptr, B5, pair4, nullptr, dinvP, TL, 256, 512, 0, 8);   // pp2 | pr2 from p
  STAGE(rowptrP, colP, dinvP, pp2_b, pr2_b, rowptrTP, colTP, icP, B4,
        nullptr, nullptr, PK + 512, 1024, PN, 0);

  // ---- P6: fuse precompute ----
  hipLaunchKernelGGL(ln_elu, rgrid, blk, 0, stream, B0, B4, PN);       // fp
  GEMM(nullptr, B4, Wsfc, nullptr, nullptr, PK + 256, 256, 1024, 2, 4); // x_fp -> slot1
  GEMM(nullptr, Ep, Wskp, nullptr, nullptr, PK + 768, 256, 1024, 0, 4); // x_skip -> slot3

  // ---- P7: pair epilogue (one pair per 32-lane half-wave) ----
  hipLaunchKernelGGL(pair_kernel, dim3((NPAIRN + 7) / 8), blk, 0, stream,
                     PK, idx1, idx2, wR, wI, outp, NPAIRN);
}

// Round 12
// 816.780 us; speedup vs baseline: 1.3381x; 1.1110x over previous
//
#include <hip/hip_runtime.h>
#include <hip/hip_bf16.h>
#include <math.h>

#define PN 20000
#define DN 20000
#define SEQK 1024
#define EPPI 640000
#define EDDI 640000
#define EDTI 400000
#define NPAIRN 100000
#define RPB 128            // rows per bucket
#define NBUCK 157          // ceil(20000/128)
#define CH 4096            // edges per sort block
#define NBLKMAX 157        // ceil(640000/4096)
#define RBX 40             // row-blocks per XCD = ceil(313/8)

typedef float4 f4;
using bf16x8 = __attribute__((ext_vector_type(8))) __bf16;
using bf16x4 = __attribute__((ext_vector_type(4))) __bf16;
using f32x4v = __attribute__((ext_vector_type(4))) float;

__device__ __forceinline__ f4 ld4(const float* p) { return *reinterpret_cast<const f4*>(p); }
__device__ __forceinline__ f4 ldb4(const __bf16* p) {
  bf16x4 v = *reinterpret_cast<const bf16x4*>(p);
  return make_float4((float)v[0], (float)v[1], (float)v[2], (float)v[3]);
}
__device__ __forceinline__ void stb4(__bf16* p, f4 v) {
  bf16x4 o;
  o[0] = (__bf16)v.x; o[1] = (__bf16)v.y; o[2] = (__bf16)v.z; o[3] = (__bf16)v.w;
  *reinterpret_cast<bf16x4*>(p) = o;
}
__device__ __forceinline__ void acc4(f4& a, f4 b) { a.x+=b.x; a.y+=b.y; a.z+=b.z; a.w+=b.w; }
__device__ __forceinline__ void acc4s(f4& a, f4 b, float s) { a.x+=s*b.x; a.y+=s*b.y; a.z+=s*b.z; a.w+=s*b.w; }

__device__ __forceinline__ void wave_ln(f4& x) {
  float s  = x.x + x.y + x.z + x.w;
  float ss = x.x*x.x + x.y*x.y + x.z*x.z + x.w*x.w;
#pragma unroll
  for (int o = 32; o; o >>= 1) { s += __shfl_xor(s, o, 64); ss += __shfl_xor(ss, o, 64); }
  float m = s * (1.f/256.f);
  float v = ss * (1.f/256.f) - m*m;
  float r = rsqrtf(v + 1e-5f);
  x.x = (x.x-m)*r; x.y = (x.y-m)*r; x.z = (x.z-m)*r; x.w = (x.w-m)*r;
}

// LN over 256 feats held as 8 floats/lane across a 32-lane half-wave.
__device__ __forceinline__ void ln8(float* v) {
  float s = 0.f, ss = 0.f;
#pragma unroll
  for (int i = 0; i < 8; ++i) { s += v[i]; ss += v[i]*v[i]; }
#pragma unroll
  for (int o = 16; o; o >>= 1) { s += __shfl_xor(s, o, 64); ss += __shfl_xor(ss, o, 64); }
  float m = s * (1.f/256.f);
  float var = ss * (1.f/256.f) - m*m;
  float r = rsqrtf(var + 1e-5f);
#pragma unroll
  for (int i = 0; i < 8; ++i) v[i] = (v[i]-m)*r;
}

// ---------------- fp32 -> bf16 converter (weights + embeddings, 19 jobs) ----------------
struct CPack { const float* src[19]; __bf16* dst[19]; int n[19]; };
__global__ __launch_bounds__(256) void convert_all(CPack p) {
  const int wi = blockIdx.y;
  const int n = p.n[wi];
  const float* s = p.src[wi];
  __bf16* d = p.dst[wi];
  for (int i = (blockIdx.x * 256 + threadIdx.x) * 4; i < n; i += gridDim.x * 256 * 4) {
    f4 v = ld4(s + i);
    stb4(d + i, v);
  }
}

// ---------------- batched MFMA GEMM, XCD-swizzled 1D grid per job ----------------
struct GB {
  const __bf16* X[6]; int lda[6];
  const __bf16* Wt[6]; const float* bias[6]; const float* scale[6];
  __bf16* out[6]; int K[6]; int ostride[6]; int act[6]; int ncol[6];
};

__global__ __launch_bounds__(256) void gemm_batch(GB gb) {
  const int y = blockIdx.y;
  const int ncol = gb.ncol[y];
  const int bid = blockIdx.x;
  if (bid >= 8 * RBX * ncol) return;
  const int xcd = bid & 7;
  const int j = bid >> 3;
  const int row_blk = xcd * RBX + j / ncol;
  const int col_blk = j % ncol;
  const int M = PN;
  if (row_blk * 64 >= M) return;

  const __bf16* X  = gb.X[y];
  const __bf16* Wt = gb.Wt[y];
  const float* bias = gb.bias[y];
  const float* scale = gb.scale[y];
  __bf16* outb = gb.out[y];
  const int lda = gb.lda[y];
  const int K = gb.K[y];
  const int ostride = gb.ostride[y];
  const int act = gb.act[y];

  const int tid = threadIdx.x;
  const int lane = tid & 63;
  const int w = tid >> 6;
  const int r0 = row_blk * 64 + (w >> 1) * 32;
  const int c0 = col_blk * 64 + (w & 1) * 32;
  const int l15 = lane & 15;
  const int lk = (lane >> 4) * 8;

  f32x4v acc[2][2];
#pragma unroll
  for (int m = 0; m < 2; ++m)
#pragma unroll
    for (int n = 0; n < 2; ++n) { acc[m][n][0]=0.f; acc[m][n][1]=0.f; acc[m][n][2]=0.f; acc[m][n][3]=0.f; }

  int ra = min(r0 + l15, M - 1);
  int rb = min(r0 + 16 + l15, M - 1);
  const __bf16* xa = X + (size_t)ra * lda + lk;
  const __bf16* xb = X + (size_t)rb * lda + lk;
  const __bf16* wa = Wt + (size_t)(c0 + l15) * K + lk;
  const __bf16* wc = Wt + (size_t)(c0 + 16 + l15) * K + lk;

#pragma unroll 2
  for (int k0 = 0; k0 < K; k0 += 32) {
    bf16x8 a0 = *reinterpret_cast<const bf16x8*>(xa + k0);
    bf16x8 a1 = *reinterpret_cast<const bf16x8*>(xb + k0);
    bf16x8 b0 = *reinterpret_cast<const bf16x8*>(wa + k0);
    bf16x8 b1 = *reinterpret_cast<const bf16x8*>(wc + k0);
    acc[0][0] = __builtin_amdgcn_mfma_f32_16x16x32_bf16(a0, b0, acc[0][0], 0, 0, 0);
    acc[0][1] = __builtin_amdgcn_mfma_f32_16x16x32_bf16(a0, b1, acc[0][1], 0, 0, 0);
    acc[1][0] = __builtin_amdgcn_mfma_f32_16x16x32_bf16(a1, b0, acc[1][0], 0, 0, 0);
    acc[1][1] = __builtin_amdgcn_mfma_f32_16x16x32_bf16(a1, b1, acc[1][1], 0, 0, 0);
  }

  const int rowbase = r0 + (lane >> 4) * 4;
#pragma unroll
  for (int m = 0; m < 2; ++m) {
#pragma unroll
    for (int i = 0; i < 4; ++i) {
      int row = rowbase + m * 16 + i;
      if (row >= M) continue;
#pragma unroll
      for (int n2 = 0; n2 < 2; ++n2) {
        int col = c0 + n2 * 16 + l15;
        float v = acc[m][n2][i];
        if (bias) v += bias[col];
        if (act == 1) v = fmaxf(v, 0.f);
        else if (act == 2) v = v > 0.f ? v : (expf(v) - 1.f);
        if (scale && col < 256) v *= scale[row];
        outb[(size_t)row * ostride + col] = (__bf16)v;
      }
    }
  }
}

// ---------------- contention-free two-level counting-sort CSR build ----------------
struct GPack {
  const int* src[4]; const int* dst[4]; int nE[4];
  int* col[4]; int* rowptr[4]; float* outdeg[4];  // dinvP,dinvD,icD,icP
  unsigned* stg[4];
  int* bh;      // [4][NBUCK][NBLKMAX]
  int* bbase;   // [4][NBUCK+1]
};

__global__ __launch_bounds__(256) void sort_hist(GPack g) {
  __shared__ int h[NBUCK];
  const int gi = blockIdx.y, blk = blockIdx.x;
  const int t = threadIdx.x;
  for (int i = t; i < NBUCK; i += 256) h[i] = 0;
  __syncthreads();
  const int base = blk * CH, nE = g.nE[gi];
  const int* dst = g.dst[gi];
#pragma unroll
  for (int i = 0; i < CH / 256; ++i) {
    int e = base + i * 256 + t;
    if (e < nE) atomicAdd(&h[dst[e] >> 7], 1);
  }
  __syncthreads();
  int* bh = g.bh + (size_t)gi * NBUCK * NBLKMAX;
  for (int i = t; i < NBUCK; i += 256) bh[i * NBLKMAX + blk] = h[i];
}

__global__ __launch_bounds__(1024) void sort_scan(GPack g) {
  __shared__ int sums[1024];
  const int gi = blockIdx.y;
  int* bh = g.bh + (size_t)gi * NBUCK * NBLKMAX;
  int* bbase = g.bbase + gi * (NBUCK + 1);
  const int L = NBUCK * NBLKMAX;
  const int t = threadIdx.x;
  const int chunk = (L + 1023) / 1024;
  const int b = t * chunk;
  const int e = min(b + chunk, L);
  int s = 0;
  for (int i = b; i < e; ++i) s += bh[i];
  sums[t] = s;
  __syncthreads();
  for (int o = 1; o < 1024; o <<= 1) {
    int u = (t >= o) ? sums[t - o] : 0;
    __syncthreads();
    sums[t] += u;
    __syncthreads();
  }
  int run = sums[t] - s;
  for (int i = b; i < e; ++i) {
    if (i % NBLKMAX == 0) bbase[i / NBLKMAX] = run;
    int old = bh[i];
    bh[i] = run;
    run += old;
  }
  if (t == 0) bbase[NBUCK] = g.nE[gi];
}

__global__ __launch_bounds__(256) void sort_scatter(GPack g) {
  __shared__ int cur[NBUCK];
  const int gi = blockIdx.y, blk = blockIdx.x;
  const int t = threadIdx.x;
  const int* bh = g.bh + (size_t)gi * NBUCK * NBLKMAX;
  for (int i = t; i < NBUCK; i += 256) cur[i] = bh[i * NBLKMAX + blk];
  __syncthreads();
  const int base = blk * CH, nE = g.nE[gi];
  const int* src = g.src[gi];
  const int* dst = g.dst[gi];
  unsigned* stg = g.stg[gi];
#pragma unroll
  for (int i = 0; i < CH / 256; ++i) {
    int e = base + i * 256 + t;
    if (e < nE) {
      int d = dst[e];
      int bkt = d >> 7;
      int pos = atomicAdd(&cur[bkt], 1);
      stg[pos] = ((unsigned)src[e] << 7) | (unsigned)(d & 127);
    }
  }
}

__global__ __launch_bounds__(256) void bucket_csr(GPack g) {
  const int gi = blockIdx.y;
  const int b = blockIdx.x;
  const int base = g.bbase[gi * (NBUCK + 1) + b];
  const int cnt  = g.bbase[gi * (NBUCK + 1) + b + 1] - base;
  __shared__ int h[RPB], sc[RPB];
  const int t = threadIdx.x;
  if (t < RPB) h[t] = 0;
  __syncthreads();
  const unsigned* st = g.stg[gi] + base;
  const int row0 = b * RPB;
  for (int i = t; i < cnt; i += 256) atomicAdd(&h[st[i] & 127u], 1);
  __syncthreads();
  if (t == 0) { int run = 0; for (int r = 0; r < RPB; ++r) { sc[r] = run; run += h[r]; } }
  __syncthreads();
  const int rows = min(RPB, PN - row0);
  if (t < rows) {
    g.rowptr[gi][row0 + t] = base + sc[t];
    float c = (float)h[t];
    g.outdeg[gi][row0 + t] = (gi < 2) ? rsqrtf(c + 1.f) : (1.f / fmaxf(c, 1.f));
  }
  if (b == 0 && t == 0) g.rowptr[gi][PN] = g.nE[gi];
  __syncthreads();
  if (t < RPB) h[t] = sc[t];
  __syncthreads();
  for (int i = t; i < cnt; i += 256) {
    unsigned v = st[i];
    int pos = atomicAdd(&h[v & 127u], 1);
    g.col[gi][base + pos] = (int)(v >> 7);
  }
}

// ---------------- batched fused GCN stage (mode 0) / ln_elu (mode 1) ----------------
struct SB {
  const int* rpG[4]; const int* clG[4]; const float* dinv[4];
  const __bf16* T[4]; int tstr[4];
  const float* gbias[4]; const float* linb[4];
  const int* rpS[4]; const int* clS[4]; const float* ic[4]; const __bf16* Pt[4];
  const float* lw[4]; const float* lb[4];
  __bf16* out[4]; int ostr[4]; int n[4]; int act[4]; int mode[4];
};

__global__ __launch_bounds__(256) void stage_batch(SB sb) {
  const int y = blockIdx.y;
  int row = (blockIdx.x * blockDim.x + threadIdx.x) >> 6;
  if (row >= sb.n[y]) return;
  int lane = threadIdx.x & 63;
  int o = lane * 4;
  const __bf16* T = sb.T[y];
  const int tstr = sb.tstr[y];
  __bf16* out = sb.out[y];
  const int ostr = sb.ostr[y];

  if (sb.mode[y] == 1) {   // fp = elu(LN(T_row))
    f4 x = ldb4(T + (size_t)row * tstr + o);
    wave_ln(x);
    x.x = x.x > 0.f ? x.x : expf(x.x)-1.f;
    x.y = x.y > 0.f ? x.y : expf(x.y)-1.f;
    x.z = x.z > 0.f ? x.z : expf(x.z)-1.f;
    x.w = x.w > 0.f ? x.w : expf(x.w)-1.f;
    stb4(out + (size_t)row * ostr + o, x);
    return;
  }

  const int* rpG = sb.rpG[y];
  const int* clG = sb.clG[y];
  const float* dinv = sb.dinv[y];
  float dd = dinv[row];

  // T is pre-scaled by dinv (t' rows); gacc = self + neighbors, x = dd*gacc.
  f4 gacc = ldb4(T + (size_t)row * tstr + o);

  int beg = rpG[row], end = rpG[row + 1];
  int j = beg;
  for (; j + 7 < end; j += 8) {
    int s[8];
    f4 tv[8];
#pragma unroll
    for (int q = 0; q < 8; ++q) s[q] = clG[j + q];
#pragma unroll
    for (int q = 0; q < 8; ++q) tv[q] = ldb4(T + (size_t)s[q] * tstr + o);
#pragma unroll
    for (int q = 0; q < 8; ++q) acc4(gacc, tv[q]);
  }
  for (; j < end; ++j) {
    acc4(gacc, ldb4(T + (size_t)clG[j] * tstr + o));
  }

  f4 x = make_float4(0.f, 0.f, 0.f, 0.f);
  acc4s(x, gacc, dd);

  if (sb.gbias[y]) acc4(x, ld4(sb.gbias[y] + o));
  if (sb.linb[y])  acc4(x, ld4(sb.linb[y] + o));
  acc4(x, ldb4(T + (size_t)row * tstr + 256 + o));   // lin half of TL

  if (sb.rpS[y]) {
    const int* rpS = sb.rpS[y];
    const int* clS = sb.clS[y];
    const __bf16* Pt = sb.Pt[y];
    f4 s4 = make_float4(0.f, 0.f, 0.f, 0.f);
    int sbg = rpS[row], se = rpS[row + 1];
    int k = sbg;
    for (; k + 7 < se; k += 8) {
      int s[8];
      f4 tv[8];
#pragma unroll
      for (int q = 0; q < 8; ++q) s[q] = clS[k + q];
#pragma unroll
      for (int q = 0; q < 8; ++q) tv[q] = ldb4(Pt + (size_t)s[q] * 256 + o);
#pragma unroll
      for (int q = 0; q < 8; ++q) acc4(s4, tv[q]);
    }
    for (; k < se; ++k) acc4(s4, ldb4(Pt + (size_t)clS[k] * 256 + o));
    acc4s(x, s4, sb.ic[y][row]);
  }

  wave_ln(x);
  if (sb.lw[y]) {
    f4 w = ld4(sb.lw[y] + o), b = ld4(sb.lb[y] + o);
    x.x = x.x*w.x + b.x; x.y = x.y*w.y + b.y; x.z = x.z*w.z + b.z; x.w = x.w*w.w + b.w;
  }
  if (sb.act[y] == 1) {
    x.x = fmaxf(x.x, 0.f); x.y = fmaxf(x.y, 0.f); x.z = fmaxf(x.z, 0.f); x.w = fmaxf(x.w, 0.f);
  }
  stb4(out + (size_t)row * ostr + o, x);
}

// ---------------- pair epilogue: one pair per 32-lane half-wave ----------------
__global__ __launch_bounds__(256) void pair_kernel(
    const __bf16* __restrict__ PK,
    const int* __restrict__ idx1, const int* __restrict__ idx2,
    const float* __restrict__ wR, const float* __restrict__ wI,
    float* __restrict__ out, int npair)
{
  int pid = (blockIdx.x * 256 + threadIdx.x) >> 5;
  if (pid >= npair) return;
  int l = threadIdx.x & 31;
  int f = l * 8;
  const __bf16* r1 = PK + (size_t)idx1[pid] * 1024;
  const __bf16* r2 = PK + (size_t)idx2[pid] * 1024;

  bf16x8 a0 = *reinterpret_cast<const bf16x8*>(r1 + f);
  bf16x8 a1 = *reinterpret_cast<const bf16x8*>(r1 + 256 + f);
  bf16x8 a2 = *reinterpret_cast<const bf16x8*>(r1 + 512 + f);
  bf16x8 a3 = *reinterpret_cast<const bf16x8*>(r1 + 768 + f);
  bf16x8 b0 = *reinterpret_cast<const bf16x8*>(r2 + f);
  bf16x8 b1 = *reinterpret_cast<const bf16x8*>(r2 + 256 + f);
  bf16x8 b2 = *reinterpret_cast<const bf16x8*>(r2 + 512 + f);
  bf16x8 b3 = *reinterpret_cast<const bf16x8*>(r2 + 768 + f);

  float R1[8], I1[8], R2[8], I2[8];
#pragma unroll
  for (int i = 0; i < 8; ++i) {
    R1[i] = (float)a0[i] + (float)b1[i];
    I1[i] = (float)a2[i] + (float)b3[i];
    R2[i] = (float)a3[i] + (float)b2[i];
    I2[i] = (float)a1[i] + (float)b0[i];
  }
  ln8(R1); ln8(I1); ln8(R2); ln8(I2);

  float R[8], I[8];
#pragma unroll
  for (int i = 0; i < 8; ++i) {
    R[i] = R1[i]*R2[i] - I1[i]*I2[i];
    I[i] = R1[i]*I2[i] + I1[i]*R2[i];
  }
  ln8(R); ln8(I);

  f4 wr0 = ld4(wR + f), wr1 = ld4(wR + f + 4);
  f4 wi0 = ld4(wI + f), wi1 = ld4(wI + f + 4);
  float wrv[8] = {wr0.x,wr0.y,wr0.z,wr0.w, wr1.x,wr1.y,wr1.z,wr1.w};
  float wiv[8] = {wi0.x,wi0.y,wi0.z,wi0.w, wi1.x,wi1.y,wi1.z,wi1.w};
  float t = 0.f;
#pragma unroll
  for (int i = 0; i < 8; ++i) t += R[i]*(wrv[i]-wiv[i]) + I[i]*(wrv[i]+wiv[i]);
#pragma unroll
  for (int o = 16; o; o >>= 1) t += __shfl_xor(t, o, 64);
  if (l == 0) out[pid] = 1.f / (1.f + expf(-t));
}

extern "C" void kernel_launch(void* const* d_in, const int* in_sizes, int n_in,
                              void* d_out, int out_size, void* d_ws, size_t ws_size,
                              hipStream_t stream) {
  (void)in_sizes; (void)n_in; (void)out_size; (void)ws_size;
  const float* seq        = (const float*)d_in[0];
  const int*   ppi        = (const int*)d_in[1];
  const int*   ddi        = (const int*)d_in[2];
  const int*   dti        = (const int*)d_in[3];
  const int*   idx1       = (const int*)d_in[4];
  const int*   idx2       = (const int*)d_in[5];
  const float* seq_init_W = (const float*)d_in[6];
  const float* gs1_gcn_W  = (const float*)d_in[7];
  const float* gs1_gcn_b  = (const float*)d_in[8];
  const float* gs1_lin_W  = (const float*)d_in[9];
  const float* gs1_ln_w   = (const float*)d_in[10];
  const float* gs1_ln_b   = (const float*)d_in[11];
  const float* gs2_gcn_W  = (const float*)d_in[12];
  const float* gs2_gcn_b  = (const float*)d_in[13];
  const float* gs2_lin_W  = (const float*)d_in[14];
  const float* gs2_ln_w   = (const float*)d_in[15];
  const float* gs2_ln_b   = (const float*)d_in[16];
  const float* drug_emb   = (const float*)d_in[17];
  const float* prot_emb   = (const float*)d_in[18];
  const float* pp1_W = (const float*)d_in[19]; const float* pp1_b = (const float*)d_in[20];
  const float* td1_W = (const float*)d_in[21]; const float* td1_b = (const float*)d_in[22];
  const float* pr1_W = (const float*)d_in[23]; const float* pr1_b = (const float*)d_in[24];
  const float* dd1_W = (const float*)d_in[25]; const float* dd1_b = (const float*)d_in[26];
  const float* dt1_W = (const float*)d_in[27]; const float* dt1_b = (const float*)d_in[28];
  const float* dr1_W = (const float*)d_in[29]; const float* dr1_b = (const float*)d_in[30];
  const float* pp2_W = (const float*)d_in[31]; const float* pp2_b = (const float*)d_in[32];
  const float* td2_W = (const float*)d_in[33]; const float* td2_b = (const float*)d_in[34];
  const float* pr2_W = (const float*)d_in[35]; const float* pr2_b = (const float*)d_in[36];
  const float* seq_fc_W  = (const float*)d_in[43];
  const float* skip_fc_W = (const float*)d_in[44];
  const float* wR = (const float*)d_in[45];
  const float* wI = (const float*)d_in[46];
  float* outp = (float*)d_out;

  // ---------------- workspace layout ----------------
  char* base = (char*)d_ws;
  unsigned* stgP  = (unsigned*)base;                 // EPPI
  unsigned* stgD  = stgP + EPPI;
  unsigned* stgTD = stgD + EDDI;
  unsigned* stgTP = stgTD + EDTI;
  int* colP  = (int*)(stgTP + EDTI);
  int* colD  = colP + EPPI;
  int* colTD = colD + EDDI;
  int* colTP = colTD + EDTI;
  int* rowptrP  = colTP + EDTI;
  int* rowptrD  = rowptrP + PN + 1;
  int* rowptrTD = rowptrD + PN + 1;
  int* rowptrTP = rowptrTD + PN + 1;
  float* dinvP = (float*)(rowptrTP + PN + 1);
  float* dinvD = dinvP + PN;
  float* icD   = dinvD + PN;
  float* icP   = icD + PN;
  int* bh    = (int*)(icP + PN);                     // 4*NBUCK*NBLKMAX
  int* bbase = bh + 4 * NBUCK * NBLKMAX;             // 4*(NBUCK+1)

  unsigned long long waddr = (unsigned long long)(bbase + 4 * (NBUCK + 1));
  waddr = (waddr + 63ULL) & ~63ULL;
  __bf16* wb = (__bf16*)waddr;
  __bf16* Wseq  = wb;                           // [256,1024]
  __bf16* pair0 = Wseq + 256*1024;              // each pair [512,256]
  __bf16* pair1 = pair0 + 512*256;
  __bf16* pair2 = pair1 + 512*256;
  __bf16* pair3 = pair2 + 512*256;
  __bf16* pair4 = pair3 + 512*256;
  __bf16* sing  = pair4 + 512*256;
  __bf16* Wdt1  = sing;
  __bf16* Wtd1  = sing + 65536;
  __bf16* Wtd2  = sing + 2*65536;
  __bf16* Wsfc  = sing + 3*65536;
  __bf16* Wskp  = sing + 4*65536;
  const size_t NB = (size_t)PN * 256;
  __bf16* Ed    = sing + 5*65536;               // [20000,256]
  __bf16* Ep    = Ed + NB;
  __bf16* TL0   = Ep + NB;                      // [20000,512]
  __bf16* TLd   = TL0 + (size_t)PN*512;         // [20000,512]
  __bf16* TLp   = TLd + (size_t)PN*512;         // [20000,512]
  __bf16* B0    = TLp + (size_t)PN*512;         // x_seq
  __bf16* Bh    = B0 + NB;                      // h
  __bf16* B4a   = Bh + NB;                      // proj_p (4d) -> P5 proj
  __bf16* B4b   = B4a + NB;                     // proj_d (4p)
  __bf16* B4e   = B4b + NB;                     // fp
  __bf16* PK    = B4e + NB;                     // [20000][1024]: x1 | xfp | p2 | xskip
  __bf16* Eseq  = PK;                           // alias, dead after batch1
  __bf16* Bd    = PK + 0;                       // d, stride 1024 (slot0, dead before gs2 writes)
  __bf16* Bp    = PK + 512;                     // p, stride 1024 (slot2, dead before P5 writes)

  const dim3 blk(256);
  const dim3 rgrid((PN + 3) / 4);
  const dim3 sgrid(NBLKMAX, 4);
  const dim3 bgrid(NBUCK, 4);
  const dim3 ggrid(8 * RBX * 8);   // max ncol=8

  // ---- converts (1 launch, 19 jobs) ----
  {
    CPack p;
    const float* srcs[19] = { seq_init_W, gs1_gcn_W, gs1_lin_W, gs2_gcn_W, gs2_lin_W,
                              dd1_W, dr1_W, pp1_W, pr1_W, pp2_W, pr2_W,
                              dt1_W, td1_W, td2_W, seq_fc_W, skip_fc_W,
                              seq, drug_emb, prot_emb };
    __bf16* dsts[19] = { Wseq, pair0, pair0 + 65536, pair1, pair1 + 65536,
                         pair2, pair2 + 65536, pair3, pair3 + 65536, pair4, pair4 + 65536,
                         Wdt1, Wtd1, Wtd2, Wsfc, Wskp,
                         Eseq, Ed, Ep };
    for (int i = 0; i < 19; ++i) {
      p.src[i] = srcs[i]; p.dst[i] = dsts[i];
      p.n[i] = (i == 0) ? 256*1024 : (i == 16) ? PN*SEQK : (i >= 17) ? PN*256 : 256*256;
    }
    hipLaunchKernelGGL(convert_all, dim3(2048, 19), blk, 0, stream, p);
  }

  // ---- counting-sort CSR build (4 launches) ----
  GPack g;
  g.src[0] = ppi;        g.dst[0] = ppi + EPPI; g.nE[0] = EPPI;
  g.src[1] = ddi;        g.dst[1] = ddi + EDDI; g.nE[1] = EDDI;
  g.src[2] = dti + EDTI; g.dst[2] = dti;        g.nE[2] = EDTI;
  g.src[3] = dti;        g.dst[3] = dti + EDTI; g.nE[3] = EDTI;
  g.col[0] = colP;  g.col[1] = colD;  g.col[2] = colTD;  g.col[3] = colTP;
  g.rowptr[0] = rowptrP; g.rowptr[1] = rowptrD; g.rowptr[2] = rowptrTD; g.rowptr[3] = rowptrTP;
  g.outdeg[0] = dinvP; g.outdeg[1] = dinvD; g.outdeg[2] = icD; g.outdeg[3] = icP;
  g.stg[0] = stgP; g.stg[1] = stgD; g.stg[2] = stgTD; g.stg[3] = stgTP;
  g.bh = bh; g.bbase = bbase;

  hipLaunchKernelGGL(sort_hist,    sgrid, blk, 0, stream, g);
  hipLaunchKernelGGL(sort_scan,    dim3(1, 4), dim3(1024), 0, stream, g);
  hipLaunchKernelGGL(sort_scatter, sgrid, blk, 0, stream, g);
  hipLaunchKernelGGL(bucket_csr,   bgrid, blk, 0, stream, g);

  // ---- batch1: 5 GEMMs (P1, 4d-t, 4d-proj, 4p-t, 4p-proj) ----
  {
    GB b{};
    b.X[0]=Eseq; b.lda[0]=1024; b.Wt[0]=Wseq;  b.bias[0]=nullptr; b.scale[0]=nullptr; b.out[0]=B0;  b.K[0]=1024; b.ostride[0]=256; b.act[0]=1; b.ncol[0]=4;
    b.X[1]=Ed;   b.lda[1]=256;  b.Wt[1]=pair2; b.bias[1]=nullptr; b.scale[1]=dinvD;   b.out[1]=TLd; b.K[1]=256;  b.ostride[1]=512; b.act[1]=0; b.ncol[1]=8;
    b.X[2]=Ep;   b.lda[2]=256;  b.Wt[2]=Wdt1;  b.bias[2]=dt1_b;   b.scale[2]=nullptr; b.out[2]=B4a; b.K[2]=256;  b.ostride[2]=256; b.act[2]=0; b.ncol[2]=4;
    b.X[3]=Ep;   b.lda[3]=256;  b.Wt[3]=pair3; b.bias[3]=nullptr; b.scale[3]=dinvP;   b.out[3]=TLp; b.K[3]=256;  b.ostride[3]=512; b.act[3]=0; b.ncol[3]=8;
    b.X[4]=Ed;   b.lda[4]=256;  b.Wt[4]=Wtd1;  b.bias[4]=td1_b;   b.scale[4]=nullptr; b.out[4]=B4b; b.K[4]=256;  b.ostride[4]=256; b.act[4]=0; b.ncol[4]=4;
    hipLaunchKernelGGL(gemm_batch, dim3(ggrid.x, 5), blk, 0, stream, b);
  }

  // ---- P2 gemm: B0 -> TL0 (scaled t-half) ----
  {
    GB b{};
    b.X[0]=B0; b.lda[0]=256; b.Wt[0]=pair0; b.bias[0]=nullptr; b.scale[0]=dinvP; b.out[0]=TL0; b.K[0]=256; b.ostride[0]=512; b.act[0]=0; b.ncol[0]=8;
    hipLaunchKernelGGL(gemm_batch, dim3(ggrid.x, 1), blk, 0, stream, b);
  }

  // ---- stageA: {4d -> Bd, 4p -> Bp, gs1 -> Bh, ln_elu B0 -> B4e} ----
  {
    SB s{};
    s.rpG[0]=rowptrD; s.clG[0]=colD; s.dinv[0]=dinvD; s.T[0]=TLd; s.tstr[0]=512;
    s.gbias[0]=dd1_b; s.linb[0]=dr1_b; s.rpS[0]=rowptrTD; s.clS[0]=colTD; s.ic[0]=icD; s.Pt[0]=B4a;
    s.lw[0]=nullptr; s.lb[0]=nullptr; s.out[0]=Bd; s.ostr[0]=1024; s.n[0]=DN; s.act[0]=1; s.mode[0]=0;

    s.rpG[1]=rowptrP; s.clG[1]=colP; s.dinv[1]=dinvP; s.T[1]=TLp; s.tstr[1]=512;
    s.gbias[1]=pp1_b; s.linb[1]=pr1_b; s.rpS[1]=rowptrTP; s.clS[1]=colTP; s.ic[1]=icP; s.Pt[1]=B4b;
    s.lw[1]=nullptr; s.lb[1]=nullptr; s.out[1]=Bp; s.ostr[1]=1024; s.n[1]=PN; s.act[1]=1; s.mode[1]=0;

    s.rpG[2]=rowptrP; s.clG[2]=colP; s.dinv[2]=dinvP; s.T[2]=TL0; s.tstr[2]=512;
    s.gbias[2]=gs1_gcn_b; s.linb[2]=nullptr; s.rpS[2]=nullptr;
    s.lw[2]=gs1_ln_w; s.lb[2]=gs1_ln_b; s.out[2]=Bh; s.ostr[2]=256; s.n[2]=PN; s.act[2]=1; s.mode[2]=0;

    s.T[3]=B0; s.tstr[3]=256; s.out[3]=B4e; s.ostr[3]=256; s.n[3]=PN; s.mode[3]=1;
    hipLaunchKernelGGL(stage_batch, dim3(rgrid.x, 4), blk, 0, stream, s);
  }

  // ---- batch2: 5 GEMMs (P3-t, P5-t, P5-proj, xfp, xskip) ----
  {
    GB b{};
    b.X[0]=Bh;  b.lda[0]=256;  b.Wt[0]=pair1; b.bias[0]=nullptr; b.scale[0]=dinvP;   b.out[0]=TLd;      b.K[0]=256; b.ostride[0]=512;  b.act[0]=0; b.ncol[0]=8;
    b.X[1]=Bp;  b.lda[1]=1024; b.Wt[1]=pair4; b.bias[1]=nullptr; b.scale[1]=dinvP;   b.out[1]=TLp;      b.K[1]=256; b.ostride[1]=512;  b.act[1]=0; b.ncol[1]=8;
    b.X[2]=Bd;  b.lda[2]=1024; b.Wt[2]=Wtd2;  b.bias[2]=td2_b;   b.scale[2]=nullptr; b.out[2]=B4a;      b.K[2]=256; b.ostride[2]=256;  b.act[2]=0; b.ncol[2]=4;
    b.X[3]=B4e; b.lda[3]=256;  b.Wt[3]=Wsfc;  b.bias[3]=nullptr; b.scale[3]=nullptr; b.out[3]=PK + 256; b.K[3]=256; b.ostride[3]=1024; b.act[3]=2; b.ncol[3]=4;
    b.X[4]=Ep;  b.lda[4]=256;  b.Wt[4]=Wskp;  b.bias[4]=nullptr; b.scale[4]=nullptr; b.out[4]=PK + 768; b.K[4]=256; b.ostride[4]=1024; b.act[4]=0; b.ncol[4]=4;
    hipLaunchKernelGGL(gemm_batch, dim3(ggrid.x, 5), blk, 0, stream, b);
  }

  // ---- stageB: {gs2 -> PK slot0, P5 -> PK slot2} ----
  {
    SB s{};
    s.rpG[0]=rowptrP; s.clG[0]=colP; s.dinv[0]=dinvP; s.T[0]=TLd; s.tstr[0]=512;
    s.gbias[0]=gs2_gcn_b; s.linb[0]=nullptr; s.rpS[0]=nullptr;
    s.lw[0]=gs2_ln_w; s.lb[0]=gs2_ln_b; s.out[0]=PK + 0; s.ostr[0]=1024; s.n[0]=PN; s.act[0]=0; s.mode[0]=0;

    s.rpG[1]=rowptrP; s.clG[1]=colP; s.dinv[1]=dinvP; s.T[1]=TLp; s.tstr[1]=512;
    s.gbias[1]=pp2_b; s.linb[1]=pr2_b; s.rpS[1]=rowptrTP; s.clS[1]=colTP; s.ic[1]=icP; s.Pt[1]=B4a;
    s.lw[1]=nullptr; s.lb[1]=nullptr; s.out[1]=PK + 512; s.ostr[1]=1024; s.n[1]=PN; s.act[1]=0; s.mode[1]=0;
    hipLaunchKernelGGL(stage_batch, dim3(rgrid.x, 2), blk, 0, stream, s);
  }

  // ---- pair epilogue ----
  hipLaunchKernelGGL(pair_kernel, dim3((NPAIRN + 7) / 8), blk, 0, stream,
                     PK, idx1, idx2, wR, wI, outp, NPAIRN);
}